// Round 5
// baseline (233.637 us; speedup 1.0000x reference)
//
#include <hip/hip_runtime.h>
#include <hip/hip_bf16.h>
#include <cstdint>
#include <cstddef>

#define H 1024
#define V 50257
#define B 64
#define T 512

typedef __attribute__((ext_vector_type(8))) short bf16x8;
typedef __attribute__((ext_vector_type(4))) float f32x4;

__device__ __forceinline__ float sigmoidf_(float x) { return 1.0f / (1.0f + expf(-x)); }

__device__ __forceinline__ unsigned short f2bf_rn(float x) {
    __hip_bfloat16 h = __float2bfloat16(x);
    return __builtin_bit_cast(unsigned short, h);
}

__device__ __forceinline__ void gl_lds16(const float* g, float* l) {
    __builtin_amdgcn_global_load_lds(
        (const __attribute__((address_space(1))) unsigned*)g,
        (__attribute__((address_space(3))) unsigned*)l, 16, 0, 0);
}

// ---------------------------------------------------------------------------
// Gate GEMMs, one launch: z=0: Pgi = embed(seq) @ Wih^T ; z=1: Pgh = h0 @ Whh^T
__global__ __launch_bounds__(256) void gemm_gates(const int* __restrict__ seq,
                                                  const float* __restrict__ emb,
                                                  const float* __restrict__ h0,
                                                  const float* __restrict__ Wih,
                                                  const float* __restrict__ Whh,
                                                  float* __restrict__ Pgi,
                                                  float* __restrict__ Pgh) {
    __shared__ __align__(16) float As[32][68];
    __shared__ __align__(16) float Bs[32][68];
    const int z = blockIdx.z;
    const float* Bm = z ? Whh : Wih;
    float* Cp = z ? Pgh : Pgi;
    const int t = threadIdx.x;
    const int n0 = blockIdx.x * 64;
    const int k0 = blockIdx.y * 256;
    const int tm = t >> 4, tn = t & 15;
    const int N = 3 * H;
    float acc[4][4] = {};
    for (int kk = k0; kk < k0 + 256; kk += 32) {
#pragma unroll
        for (int i = 0; i < 8; ++i) {
            int idx = t + i * 256;
            int m = idx >> 5, k = idx & 31;
            As[k][m] = z ? h0[(size_t)m * H + kk + k]
                         : emb[(size_t)seq[m] * H + kk + k];
            int n = idx >> 5;
            Bs[k][n] = Bm[(size_t)(n0 + n) * H + kk + k];
        }
        __syncthreads();
#pragma unroll
        for (int k = 0; k < 32; ++k) {
            float4 a = *(const float4*)&As[k][tm * 4];
            float4 b = *(const float4*)&Bs[k][tn * 4];
            float av[4] = {a.x, a.y, a.z, a.w};
            float bv[4] = {b.x, b.y, b.z, b.w};
#pragma unroll
            for (int i = 0; i < 4; ++i)
#pragma unroll
                for (int j = 0; j < 4; ++j) acc[i][j] += av[i] * bv[j];
        }
        __syncthreads();
    }
    float* C = Cp + (size_t)blockIdx.y * 64 * N;
#pragma unroll
    for (int i = 0; i < 4; ++i)
#pragma unroll
        for (int j = 0; j < 4; ++j)
            C[(size_t)(tm * 4 + i) * N + n0 + tn * 4 + j] = acc[i][j];
}

// Generic split-K tiled GEMM (Wa / Wc), M=64, BN=64, BK=32.
template <bool BT>
__global__ __launch_bounds__(256) void gemm64(const float* __restrict__ A, int lda,
                                              const float* __restrict__ Bm, int ldb,
                                              float* __restrict__ Cp, int N, int KC) {
    __shared__ __align__(16) float As[32][68];
    __shared__ __align__(16) float Bs[32][68];
    const int t = threadIdx.x;
    const int n0 = blockIdx.x * 64;
    const int k0 = blockIdx.y * KC;
    const int tm = t >> 4, tn = t & 15;
    float acc[4][4] = {};
    for (int kk = k0; kk < k0 + KC; kk += 32) {
#pragma unroll
        for (int i = 0; i < 8; ++i) {
            int idx = t + i * 256;
            int m = idx >> 5, k = idx & 31;
            As[k][m] = A[(size_t)m * lda + kk + k];
        }
        if (BT) {
#pragma unroll
            for (int i = 0; i < 8; ++i) {
                int idx = t + i * 256;
                int n = idx >> 5, k = idx & 31;
                Bs[k][n] = Bm[(size_t)(n0 + n) * ldb + kk + k];
            }
        } else {
#pragma unroll
            for (int i = 0; i < 8; ++i) {
                int k = (t >> 6) + i * 4, n = t & 63;
                Bs[k][n] = Bm[(size_t)(kk + k) * ldb + n0 + n];
            }
        }
        __syncthreads();
#pragma unroll
        for (int k = 0; k < 32; ++k) {
            float4 a = *(const float4*)&As[k][tm * 4];
            float4 b = *(const float4*)&Bs[k][tn * 4];
            float av[4] = {a.x, a.y, a.z, a.w};
            float bv[4] = {b.x, b.y, b.z, b.w};
#pragma unroll
            for (int i = 0; i < 4; ++i)
#pragma unroll
                for (int j = 0; j < 4; ++j) acc[i][j] += av[i] * bv[j];
        }
        __syncthreads();
    }
    float* C = Cp + (size_t)blockIdx.y * 64 * N;
#pragma unroll
    for (int i = 0; i < 4; ++i)
#pragma unroll
        for (int j = 0; j < 4; ++j)
            C[(size_t)(tm * 4 + i) * N + n0 + tn * 4 + j] = acc[i][j];
}

// ---------------------------------------------------------------------------
__global__ void k_gru(const float* __restrict__ Pgi, const float* __restrict__ Pgh,
                      const float* __restrict__ bih, const float* __restrict__ bhh,
                      const float* __restrict__ h0, float* __restrict__ cat,
                      float* __restrict__ hid) {
    int i = blockIdx.x * 256 + threadIdx.x;   // 65536
    int b = i >> 10, h = i & 1023;
    float gr = bih[h], gz = bih[H + h], gn = bih[2 * H + h];
    float hr = bhh[h], hz = bhh[H + h], hn = bhh[2 * H + h];
#pragma unroll
    for (int kt = 0; kt < 4; ++kt) {
        const float* pi = Pgi + (size_t)kt * B * 3 * H + (size_t)b * 3 * H;
        const float* ph = Pgh + (size_t)kt * B * 3 * H + (size_t)b * 3 * H;
        gr += pi[h]; gz += pi[H + h]; gn += pi[2 * H + h];
        hr += ph[h]; hz += ph[H + h]; hn += ph[2 * H + h];
    }
    float r = sigmoidf_(gr + hr);
    float z = sigmoidf_(gz + hz);
    float n = tanhf(gn + r * hn);
    float hv = (1.0f - z) * n + z * h0[i];
    cat[(size_t)b * 2 * H + h] = hv;
    hid[i] = hv;
}

// ---------------------------------------------------------------------------
// Flash attention: ONE wave per (b, 8-row chunk). 4096 waves (16/CU).
__global__ __launch_bounds__(256) void k_flash(const float* __restrict__ Pu,
                                               const float* __restrict__ enc,
                                               float* __restrict__ Pm,
                                               float* __restrict__ Pl,
                                               float* __restrict__ Pc) {
    const int g = blockIdx.x * 4 + (threadIdx.x >> 6);   // 0..4095
    const int lane = threadIdx.x & 63;
    const int b = g >> 6, ch = g & 63;

    float4 uu[4];
#pragma unroll
    for (int it = 0; it < 4; ++it) {
        int col = (it * 64 + lane) * 4;
        float4 s = *(const float4*)&Pu[(size_t)b * H + col];
#pragma unroll
        for (int kt = 1; kt < 4; ++kt) {
            float4 p = *(const float4*)&Pu[(size_t)kt * B * H + (size_t)b * H + col];
            s.x += p.x; s.y += p.y; s.z += p.z; s.w += p.w;
        }
        uu[it] = s;
    }

    float m = -3.4e38f, l = 0.f;
    float4 c[4] = {{0,0,0,0},{0,0,0,0},{0,0,0,0},{0,0,0,0}};
    const float* ebase = enc + ((size_t)b * T + ch * 8) * H;

#pragma unroll 2
    for (int tt = 0; tt < 8; ++tt) {
        float4 e[4];
#pragma unroll
        for (int it = 0; it < 4; ++it)
            e[it] = *(const float4*)&ebase[(size_t)tt * H + (it * 64 + lane) * 4];
        float s = 0.f;
#pragma unroll
        for (int it = 0; it < 4; ++it)
            s += uu[it].x * e[it].x + uu[it].y * e[it].y +
                 uu[it].z * e[it].z + uu[it].w * e[it].w;
#pragma unroll
        for (int o = 32; o; o >>= 1) s += __shfl_xor(s, o, 64);
        float mn = fmaxf(m, s);
        float scale = __expf(m - mn);
        float p = __expf(s - mn);
        l = l * scale + p;
#pragma unroll
        for (int it = 0; it < 4; ++it) {
            c[it].x = fmaf(p, e[it].x, c[it].x * scale);
            c[it].y = fmaf(p, e[it].y, c[it].y * scale);
            c[it].z = fmaf(p, e[it].z, c[it].z * scale);
            c[it].w = fmaf(p, e[it].w, c[it].w * scale);
        }
        m = mn;
    }

    if (lane == 0) { Pm[g] = m; Pl[g] = l; }
#pragma unroll
    for (int it = 0; it < 4; ++it)
        *(float4*)&Pc[(size_t)g * H + (it * 64 + lane) * 4] = c[it];
}

// Combine 64 chunk-partials per b -> context -> cat[:, H:2H]
__global__ void k_fcomb(const float* __restrict__ Pm, const float* __restrict__ Pl,
                        const float* __restrict__ Pc, float* __restrict__ cat) {
    const int b = blockIdx.x;
    const int col = threadIdx.x * 4;
    float M = -3.4e38f;
#pragma unroll 8
    for (int i = 0; i < 64; ++i) M = fmaxf(M, Pm[b * 64 + i]);
    float L = 0.f;
    float4 cc = {0, 0, 0, 0};
#pragma unroll 4
    for (int i = 0; i < 64; ++i) {
        float wgt = __expf(Pm[b * 64 + i] - M);
        L += Pl[b * 64 + i] * wgt;
        float4 p = *(const float4*)&Pc[(size_t)(b * 64 + i) * H + col];
        cc.x += wgt * p.x; cc.y += wgt * p.y;
        cc.z += wgt * p.z; cc.w += wgt * p.w;
    }
    float inv = 1.0f / L;
    float4 o = {cc.x * inv, cc.y * inv, cc.z * inv, cc.w * inv};
    *(float4*)&cat[(size_t)b * 2 * H + H + col] = o;
}

// co = tanh(sum partials + b_c), written as bf16
__global__ void k_co(const float* __restrict__ Pc, const float* __restrict__ bc,
                     unsigned short* __restrict__ co_bf) {
    int i = blockIdx.x * 256 + threadIdx.x;
    int h = i & 1023;
    float s = bc[h];
#pragma unroll
    for (int kt = 0; kt < 4; ++kt) s += Pc[kt * (B * H) + i];
    co_bf[i] = f2bf_rn(tanhf(s));
}

// ---------------------------------------------------------------------------
// Output GEMM: out[b,v] = sum_h co[b,h]*Wo[v,h] + bo[v].  M=64, N=V, K=H.
// BN=64 v-rows (786 blocks), BK=64, 4 waves, double-buffered 2x16KB LDS,
// global_load_lds width=16, 4 blocks/CU (16 waves/CU) for phase diversity.
// Swizzle (rule #21): linear LDS dest; source fetches chunk cg = cs ^ (row&15);
// ds_read uses chunk cc ^ (row&15) with row&15 == li. K-loop unrolled x2 for
// static buf indexing.
__global__ __launch_bounds__(256, 4) void k_out_mfma(const unsigned short* __restrict__ co_bf,
                                                     const float* __restrict__ Wo,
                                                     const float* __restrict__ bo,
                                                     float* __restrict__ out) {
    __shared__ __align__(16) float Bs[2][64 * 64];   // 16 KB x2
    const int t = threadIdx.x;
    const int w = t >> 6, lane = t & 63;
    const int li = lane & 15, qu = lane >> 4;
    const int v0 = blockIdx.x * 64;

    f32x4 acc[4];
#pragma unroll
    for (int ms = 0; ms < 4; ++ms) acc[ms] = (f32x4){0.f, 0.f, 0.f, 0.f};

    // Stage one 64x64-float tile (1024 x 16B chunks): wave w issues 4 loads.
#define STAGE(BUF, KK)                                                          \
    {                                                                           \
        _Pragma("unroll")                                                       \
        for (int j = 0; j < 4; ++j) {                                           \
            int cidx = (w * 4 + j) * 64 + lane;                                 \
            int row = cidx >> 4, cs = cidx & 15;                                \
            int cg = cs ^ (row & 15);                                           \
            int vr = v0 + row; if (vr >= V) vr = V - 1;                         \
            const float* gp = Wo + (size_t)vr * H + (KK) + cg * 4;              \
            gl_lds16(gp, &Bs[BUF][(w * 4 + j) * 256]);                          \
        }                                                                       \
    }

    // One K-step: consume buffer BUF for K-offset KK (64 floats wide).
#define KSTEP(BUF, KK)                                                          \
    {                                                                           \
        _Pragma("unroll")                                                       \
        for (int ks = 0; ks < 2; ++ks) {                                        \
            bf16x8 af[4];                                                       \
            _Pragma("unroll")                                                   \
            for (int ms = 0; ms < 4; ++ms)                                      \
                af[ms] = *(const bf16x8*)&co_bf[(size_t)(ms * 16 + li) * H +    \
                                                (KK) + ks * 32 + qu * 8];       \
            int row = w * 16 + li;                                              \
            int cc0 = ks * 8 + qu * 2;                                          \
            float4 x0 = *(const float4*)&Bs[BUF][row * 64 + ((cc0) ^ li) * 4];  \
            float4 x1 = *(const float4*)&Bs[BUF][row * 64 + ((cc0 + 1) ^ li) * 4]; \
            bf16x8 bfr;                                                         \
            bfr[0] = (short)f2bf_rn(x0.x); bfr[1] = (short)f2bf_rn(x0.y);       \
            bfr[2] = (short)f2bf_rn(x0.z); bfr[3] = (short)f2bf_rn(x0.w);       \
            bfr[4] = (short)f2bf_rn(x1.x); bfr[5] = (short)f2bf_rn(x1.y);       \
            bfr[6] = (short)f2bf_rn(x1.z); bfr[7] = (short)f2bf_rn(x1.w);       \
            _Pragma("unroll")                                                   \
            for (int ms = 0; ms < 4; ++ms)                                      \
                acc[ms] = __builtin_amdgcn_mfma_f32_16x16x32_bf16(              \
                    af[ms], bfr, acc[ms], 0, 0, 0);                             \
        }                                                                       \
    }

    STAGE(0, 0)
    __syncthreads();

    for (int kt = 0; kt < 16; kt += 2) {
        if (kt + 1 < 16) STAGE(1, (kt + 1) * 64)
        KSTEP(0, kt * 64)
        __syncthreads();
        if (kt + 2 < 16) STAGE(0, (kt + 2) * 64)
        KSTEP(1, (kt + 1) * 64)
        __syncthreads();
    }
#undef STAGE
#undef KSTEP

    {
        int v = v0 + w * 16 + li;
        if (v < V) {
            float bov = bo[v];
#pragma unroll
            for (int ms = 0; ms < 4; ++ms)
#pragma unroll
                for (int j = 0; j < 4; ++j)
                    out[(size_t)(ms * 16 + qu * 4 + j) * V + v] = acc[ms][j] + bov;
        }
    }
}

// ---------------------------------------------------------------------------
extern "C" void kernel_launch(void* const* d_in, const int* in_sizes, int n_in,
                              void* d_out, int out_size, void* d_ws, size_t ws_size,
                              hipStream_t stream) {
    (void)in_sizes; (void)n_in; (void)out_size; (void)ws_size;
    const int*   seq = (const int*)d_in[0];
    const float* h0  = (const float*)d_in[1];
    const float* enc = (const float*)d_in[2];
    const float* emb = (const float*)d_in[3];
    const float* Wih = (const float*)d_in[4];
    const float* Whh = (const float*)d_in[5];
    const float* bih = (const float*)d_in[6];
    const float* bhh = (const float*)d_in[7];
    const float* Wa  = (const float*)d_in[8];
    // d_in[9] = b_a: softmax over t is invariant to the per-b constant h·b_a -> unused
    const float* Wc  = (const float*)d_in[10];
    const float* bc  = (const float*)d_in[11];
    const float* Wo  = (const float*)d_in[12];
    const float* bo  = (const float*)d_in[13];

    float* out = (float*)d_out;
    float* hid = out + (size_t)B * V;

    float* ws   = (float*)d_ws;
    float* Pgi  = ws;                     // 786432
    float* Pgh  = Pgi + 786432;           // 786432
    float* cat  = Pgh + 786432;           // 131072
    float* Pu   = cat + 131072;           // 262144
    float* Pm   = Pu + 262144;            // 4096
    float* Pl   = Pm + 4096;              // 4096
    float* Pc   = Pl + 4096;              // 4194304 (16 MB)
    float* Pcg  = Pc + 4194304;           // 262144
    unsigned short* co_bf = (unsigned short*)(Pcg + 262144);  // 65536 ushorts

    gemm_gates<<<dim3(48, 4, 2), 256, 0, stream>>>(seq, emb, h0, Wih, Whh, Pgi, Pgh);
    k_gru<<<256, 256, 0, stream>>>(Pgi, Pgh, bih, bhh, h0, cat, hid);
    gemm64<false><<<dim3(16, 4), 256, 0, stream>>>(cat, 2 * H, Wa, H, Pu, H, 256);
    k_flash<<<1024, 256, 0, stream>>>(Pu, enc, Pm, Pl, Pc);
    k_fcomb<<<64, 256, 0, stream>>>(Pm, Pl, Pc, cat);
    gemm64<true><<<dim3(16, 4), 256, 0, stream>>>(cat, 2 * H, Wc, 2 * H, Pcg, H, 512);
    k_co<<<256, 256, 0, stream>>>(Pcg, bc, co_bf);
    k_out_mfma<<<(V + 63) / 64, 256, 0, stream>>>(co_bf, Wo, bo, out);
}

// Round 6
// 160.612 us; speedup vs baseline: 1.4547x; 1.4547x over previous
//
#include <hip/hip_runtime.h>
#include <hip/hip_bf16.h>
#include <cstdint>
#include <cstddef>

#define H 1024
#define V 50257
#define B 64
#define T 512

typedef __attribute__((ext_vector_type(8))) short bf16x8;
typedef __attribute__((ext_vector_type(4))) float f32x4;

__device__ __forceinline__ float sigmoidf_(float x) { return 1.0f / (1.0f + expf(-x)); }

__device__ __forceinline__ unsigned short f2bf_rn(float x) {
    __hip_bfloat16 h = __float2bfloat16(x);
    return __builtin_bit_cast(unsigned short, h);
}

__device__ __forceinline__ void gl_lds16(const float* g, float* l) {
    __builtin_amdgcn_global_load_lds(
        (const __attribute__((address_space(1))) unsigned*)g,
        (__attribute__((address_space(3))) unsigned*)l, 16, 0, 0);
}

// ---------------------------------------------------------------------------
// Prep: X_bf = bf16(emb[seq]); h0_bf = bf16(h0)
__global__ void k_prep(const int* __restrict__ seq, const float* __restrict__ emb,
                       const float* __restrict__ h0,
                       unsigned short* __restrict__ X_bf,
                       unsigned short* __restrict__ h0_bf) {
    int i = blockIdx.x * 256 + threadIdx.x;   // 65536
    int b = i >> 10, h = i & 1023;
    X_bf[i] = f2bf_rn(emb[(size_t)seq[b] * H + h]);
    h0_bf[i] = f2bf_rn(h0[i]);
}

// ---------------------------------------------------------------------------
// Small-GEMM via bf16 MFMA, B row-major-in-K ("BT=true" layout).
// C[m,n] = sum_k A[m,k] * Bm[n,k].  M=64, BN=128, K-chunk KC (64-wide steps).
// A: bf16, direct global.  B: fp32, staged via global_load_lds (rule #21
// swizzle: linear LDS dest, source chunk cg = cs ^ (row&15), read cc^(row&15)).
// blockIdx.z selects (A0,B0,C0) / (A1,B1,C1). Writes split-K partials.
__global__ __launch_bounds__(256) void k_mfma_bt(
    const unsigned short* __restrict__ A0, const unsigned short* __restrict__ A1, int lda,
    const float* __restrict__ B0, const float* __restrict__ B1, int ldb,
    float* __restrict__ C0, float* __restrict__ C1, int N, int KC) {
    __shared__ __align__(16) float Bs[2][128 * 64];   // 32 KB x2
    const unsigned short* A = blockIdx.z ? A1 : A0;
    const float* Bm = blockIdx.z ? B1 : B0;
    float* C = (blockIdx.z ? C1 : C0) + (size_t)blockIdx.y * 64 * N;
    const int t = threadIdx.x;
    const int w = t >> 6, lane = t & 63;
    const int li = lane & 15, qu = lane >> 4;
    const int n0 = blockIdx.x * 128;
    const int k0 = blockIdx.y * KC;
    const int nsteps = KC >> 6;

    f32x4 acc[4][2];
#pragma unroll
    for (int ms = 0; ms < 4; ++ms)
#pragma unroll
        for (int nt = 0; nt < 2; ++nt) acc[ms][nt] = (f32x4){0.f, 0.f, 0.f, 0.f};

#define STG(BUF, KK)                                                            \
    {                                                                           \
        _Pragma("unroll")                                                       \
        for (int j = 0; j < 8; ++j) {                                           \
            int cidx = (w * 8 + j) * 64 + lane;                                 \
            int row = cidx >> 4, cs = cidx & 15;                                \
            int cg = cs ^ (row & 15);                                           \
            const float* gp = Bm + (size_t)(n0 + row) * ldb + (KK) + cg * 4;    \
            gl_lds16(gp, &Bs[BUF][(w * 8 + j) * 256]);                          \
        }                                                                       \
    }

    STG(0, k0)
    __syncthreads();

    for (int kt = 0; kt < nsteps; ++kt) {
        const int buf = kt & 1;
        if (kt + 1 < nsteps) STG(buf ^ 1, k0 + (kt + 1) * 64)

        const int kk = k0 + kt * 64;
#pragma unroll
        for (int ks = 0; ks < 2; ++ks) {
            bf16x8 af[4];
#pragma unroll
            for (int ms = 0; ms < 4; ++ms)
                af[ms] = *(const bf16x8*)&A[(size_t)(ms * 16 + li) * lda + kk + ks * 32 + qu * 8];
#pragma unroll
            for (int nt = 0; nt < 2; ++nt) {
                int row = w * 32 + nt * 16 + li;
                int cc0 = ks * 8 + qu * 2;
                float4 x0 = *(const float4*)&Bs[buf][row * 64 + ((cc0)     ^ (row & 15)) * 4];
                float4 x1 = *(const float4*)&Bs[buf][row * 64 + ((cc0 + 1) ^ (row & 15)) * 4];
                bf16x8 bfr;
                bfr[0] = (short)f2bf_rn(x0.x); bfr[1] = (short)f2bf_rn(x0.y);
                bfr[2] = (short)f2bf_rn(x0.z); bfr[3] = (short)f2bf_rn(x0.w);
                bfr[4] = (short)f2bf_rn(x1.x); bfr[5] = (short)f2bf_rn(x1.y);
                bfr[6] = (short)f2bf_rn(x1.z); bfr[7] = (short)f2bf_rn(x1.w);
#pragma unroll
                for (int ms = 0; ms < 4; ++ms)
                    acc[ms][nt] = __builtin_amdgcn_mfma_f32_16x16x32_bf16(
                        af[ms], bfr, acc[ms][nt], 0, 0, 0);
            }
        }
        __syncthreads();
    }
#undef STG

#pragma unroll
    for (int nt = 0; nt < 2; ++nt) {
        int col = n0 + w * 32 + nt * 16 + li;
#pragma unroll
        for (int ms = 0; ms < 4; ++ms)
#pragma unroll
            for (int j = 0; j < 4; ++j)
                C[(size_t)(ms * 16 + qu * 4 + j) * N + col] = acc[ms][nt][j];
    }
}

// ---------------------------------------------------------------------------
// u-GEMM (B column-major-in-K): Pu[m,n] += sum_k h[m,k] * Wa[k,n].
// Wa is 4 MB (L2/L3-resident): direct strided global loads, no LDS.
__global__ __launch_bounds__(256) void k_mfma_wa(const unsigned short* __restrict__ cat_bf,
                                                 const float* __restrict__ Wa,
                                                 float* __restrict__ Pu) {
    const int t = threadIdx.x;
    const int w = t >> 6, lane = t & 63;
    const int li = lane & 15, qu = lane >> 4;
    const int n0 = blockIdx.x * 128;
    const int k0 = blockIdx.y * 256;

    f32x4 acc[4][2];
#pragma unroll
    for (int ms = 0; ms < 4; ++ms)
#pragma unroll
        for (int nt = 0; nt < 2; ++nt) acc[ms][nt] = (f32x4){0.f, 0.f, 0.f, 0.f};

    for (int kt = 0; kt < 4; ++kt) {
        const int kk = k0 + kt * 64;
#pragma unroll
        for (int ks = 0; ks < 2; ++ks) {
            bf16x8 af[4];
#pragma unroll
            for (int ms = 0; ms < 4; ++ms)
                af[ms] = *(const bf16x8*)&cat_bf[(size_t)(ms * 16 + li) * 2048 + kk + ks * 32 + qu * 8];
            const int kb = kk + ks * 32 + qu * 8;
#pragma unroll
            for (int nt = 0; nt < 2; ++nt) {
                int col = n0 + w * 32 + nt * 16 + li;
                bf16x8 bfr;
#pragma unroll
                for (int e = 0; e < 8; ++e)
                    bfr[e] = (short)f2bf_rn(Wa[(size_t)(kb + e) * H + col]);
#pragma unroll
                for (int ms = 0; ms < 4; ++ms)
                    acc[ms][nt] = __builtin_amdgcn_mfma_f32_16x16x32_bf16(
                        af[ms], bfr, acc[ms][nt], 0, 0, 0);
            }
        }
    }
    float* C = Pu + (size_t)blockIdx.y * 64 * H;
#pragma unroll
    for (int nt = 0; nt < 2; ++nt) {
        int col = n0 + w * 32 + nt * 16 + li;
#pragma unroll
        for (int ms = 0; ms < 4; ++ms)
#pragma unroll
            for (int j = 0; j < 4; ++j)
                C[(size_t)(ms * 16 + qu * 4 + j) * H + col] = acc[ms][nt][j];
    }
}

// ---------------------------------------------------------------------------
// GRU combine: fp32 partial sums -> h. Writes hid (fp32) and cat_bf[:, :H] (bf16).
__global__ void k_gru(const float* __restrict__ Pgi, const float* __restrict__ Pgh,
                      const float* __restrict__ bih, const float* __restrict__ bhh,
                      const float* __restrict__ h0, unsigned short* __restrict__ cat_bf,
                      float* __restrict__ hid) {
    int i = blockIdx.x * 256 + threadIdx.x;   // 65536
    int b = i >> 10, h = i & 1023;
    float gr = bih[h], gz = bih[H + h], gn = bih[2 * H + h];
    float hr = bhh[h], hz = bhh[H + h], hn = bhh[2 * H + h];
#pragma unroll
    for (int kt = 0; kt < 4; ++kt) {
        const float* pi = Pgi + (size_t)kt * B * 3 * H + (size_t)b * 3 * H;
        const float* ph = Pgh + (size_t)kt * B * 3 * H + (size_t)b * 3 * H;
        gr += pi[h]; gz += pi[H + h]; gn += pi[2 * H + h];
        hr += ph[h]; hz += ph[H + h]; hn += ph[2 * H + h];
    }
    float r = sigmoidf_(gr + hr);
    float z = sigmoidf_(gz + hz);
    float n = tanhf(gn + r * hn);
    float hv = (1.0f - z) * n + z * h0[i];
    cat_bf[(size_t)b * 2048 + h] = f2bf_rn(hv);
    hid[i] = hv;
}

// ---------------------------------------------------------------------------
// Flash attention: ONE wave per (b, 8-row chunk). 4096 waves (16/CU).
__global__ __launch_bounds__(256) void k_flash(const float* __restrict__ Pu,
                                               const float* __restrict__ enc,
                                               float* __restrict__ Pm,
                                               float* __restrict__ Pl,
                                               float* __restrict__ Pc) {
    const int g = blockIdx.x * 4 + (threadIdx.x >> 6);   // 0..4095
    const int lane = threadIdx.x & 63;
    const int b = g >> 6, ch = g & 63;

    float4 uu[4];
#pragma unroll
    for (int it = 0; it < 4; ++it) {
        int col = (it * 64 + lane) * 4;
        float4 s = *(const float4*)&Pu[(size_t)b * H + col];
#pragma unroll
        for (int kt = 1; kt < 4; ++kt) {
            float4 p = *(const float4*)&Pu[(size_t)kt * B * H + (size_t)b * H + col];
            s.x += p.x; s.y += p.y; s.z += p.z; s.w += p.w;
        }
        uu[it] = s;
    }

    float m = -3.4e38f, l = 0.f;
    float4 c[4] = {{0,0,0,0},{0,0,0,0},{0,0,0,0},{0,0,0,0}};
    const float* ebase = enc + ((size_t)b * T + ch * 8) * H;

#pragma unroll 2
    for (int tt = 0; tt < 8; ++tt) {
        float4 e[4];
#pragma unroll
        for (int it = 0; it < 4; ++it)
            e[it] = *(const float4*)&ebase[(size_t)tt * H + (it * 64 + lane) * 4];
        float s = 0.f;
#pragma unroll
        for (int it = 0; it < 4; ++it)
            s += uu[it].x * e[it].x + uu[it].y * e[it].y +
                 uu[it].z * e[it].z + uu[it].w * e[it].w;
#pragma unroll
        for (int o = 32; o; o >>= 1) s += __shfl_xor(s, o, 64);
        float mn = fmaxf(m, s);
        float scale = __expf(m - mn);
        float p = __expf(s - mn);
        l = l * scale + p;
#pragma unroll
        for (int it = 0; it < 4; ++it) {
            c[it].x = fmaf(p, e[it].x, c[it].x * scale);
            c[it].y = fmaf(p, e[it].y, c[it].y * scale);
            c[it].z = fmaf(p, e[it].z, c[it].z * scale);
            c[it].w = fmaf(p, e[it].w, c[it].w * scale);
        }
        m = mn;
    }

    if (lane == 0) { Pm[g] = m; Pl[g] = l; }
#pragma unroll
    for (int it = 0; it < 4; ++it)
        *(float4*)&Pc[(size_t)g * H + (it * 64 + lane) * 4] = c[it];
}

// Combine 64 chunk-partials per b -> context -> cat_bf[:, H:2H]
__global__ void k_fcomb(const float* __restrict__ Pm, const float* __restrict__ Pl,
                        const float* __restrict__ Pc, unsigned short* __restrict__ cat_bf) {
    const int b = blockIdx.x;
    const int col = threadIdx.x * 4;
    float M = -3.4e38f;
#pragma unroll 8
    for (int i = 0; i < 64; ++i) M = fmaxf(M, Pm[b * 64 + i]);
    float L = 0.f;
    float4 cc = {0, 0, 0, 0};
#pragma unroll 4
    for (int i = 0; i < 64; ++i) {
        float wgt = __expf(Pm[b * 64 + i] - M);
        L += Pl[b * 64 + i] * wgt;
        float4 p = *(const float4*)&Pc[(size_t)(b * 64 + i) * H + col];
        cc.x += wgt * p.x; cc.y += wgt * p.y;
        cc.z += wgt * p.z; cc.w += wgt * p.w;
    }
    float inv = 1.0f / L;
    ushort4 o;
    o.x = f2bf_rn(cc.x * inv); o.y = f2bf_rn(cc.y * inv);
    o.z = f2bf_rn(cc.z * inv); o.w = f2bf_rn(cc.w * inv);
    *(ushort4*)&cat_bf[(size_t)b * 2048 + 1024 + col] = o;
}

// co = tanh(sum partials + b_c), written as bf16
__global__ void k_co(const float* __restrict__ Pc, const float* __restrict__ bc,
                     unsigned short* __restrict__ co_bf) {
    int i = blockIdx.x * 256 + threadIdx.x;
    int h = i & 1023;
    float s = bc[h];
#pragma unroll
    for (int kt = 0; kt < 4; ++kt) s += Pc[kt * (B * H) + i];
    co_bf[i] = f2bf_rn(tanhf(s));
}

// ---------------------------------------------------------------------------
// Output GEMM (round-3 verbatim): out[b,v] = sum_h co[b,h]*Wo[v,h] + bo[v].
// BN=128 v-rows, BK=64, 4 waves, double-buffered 2x32KB LDS via
// global_load_lds width=16, rule-#21 swizzle.
__global__ __launch_bounds__(256) void k_out_mfma(const unsigned short* __restrict__ co_bf,
                                                  const float* __restrict__ Wo,
                                                  const float* __restrict__ bo,
                                                  float* __restrict__ out) {
    __shared__ __align__(16) float Bs[2][128 * 64];   // 32 KB x2
    const int t = threadIdx.x;
    const int w = t >> 6, lane = t & 63;
    const int li = lane & 15, qu = lane >> 4;
    const int v0 = blockIdx.x * 128;

    f32x4 acc[4][2];
#pragma unroll
    for (int ms = 0; ms < 4; ++ms)
#pragma unroll
        for (int nt = 0; nt < 2; ++nt) acc[ms][nt] = (f32x4){0.f, 0.f, 0.f, 0.f};

#define STAGE(BUF, KK)                                                          \
    {                                                                           \
        _Pragma("unroll")                                                       \
        for (int j = 0; j < 8; ++j) {                                           \
            int cidx = (w * 8 + j) * 64 + lane;                                 \
            int row = cidx >> 4, cs = cidx & 15;                                \
            int cg = cs ^ (row & 15);                                           \
            int vr = v0 + row; if (vr >= V) vr = V - 1;                         \
            const float* gp = Wo + (size_t)vr * H + (KK) + cg * 4;              \
            gl_lds16(gp, &Bs[BUF][(w * 8 + j) * 256]);                          \
        }                                                                       \
    }

    STAGE(0, 0)
    __syncthreads();

    for (int kt = 0; kt < 16; ++kt) {
        const int buf = kt & 1;
        if (kt < 15) STAGE(buf ^ 1, (kt + 1) * 64)

        const int kk = kt * 64;
#pragma unroll
        for (int ks = 0; ks < 2; ++ks) {
            bf16x8 af[4];
#pragma unroll
            for (int ms = 0; ms < 4; ++ms)
                af[ms] = *(const bf16x8*)&co_bf[(size_t)(ms * 16 + li) * H + kk + ks * 32 + qu * 8];
#pragma unroll
            for (int nt = 0; nt < 2; ++nt) {
                int row = w * 32 + nt * 16 + li;
                int cc0 = ks * 8 + qu * 2;
                float4 x0 = *(const float4*)&Bs[buf][row * 64 + ((cc0)     ^ (row & 15)) * 4];
                float4 x1 = *(const float4*)&Bs[buf][row * 64 + ((cc0 + 1) ^ (row & 15)) * 4];
                bf16x8 bfr;
                bfr[0] = (short)f2bf_rn(x0.x); bfr[1] = (short)f2bf_rn(x0.y);
                bfr[2] = (short)f2bf_rn(x0.z); bfr[3] = (short)f2bf_rn(x0.w);
                bfr[4] = (short)f2bf_rn(x1.x); bfr[5] = (short)f2bf_rn(x1.y);
                bfr[6] = (short)f2bf_rn(x1.z); bfr[7] = (short)f2bf_rn(x1.w);
#pragma unroll
                for (int ms = 0; ms < 4; ++ms)
                    acc[ms][nt] = __builtin_amdgcn_mfma_f32_16x16x32_bf16(
                        af[ms], bfr, acc[ms][nt], 0, 0, 0);
            }
        }
        __syncthreads();
    }
#undef STAGE

#pragma unroll
    for (int nt = 0; nt < 2; ++nt) {
        int v = v0 + w * 32 + nt * 16 + li;
        if (v < V) {
            float bov = bo[v];
#pragma unroll
            for (int ms = 0; ms < 4; ++ms)
#pragma unroll
                for (int j = 0; j < 4; ++j)
                    out[(size_t)(ms * 16 + qu * 4 + j) * V + v] = acc[ms][nt][j] + bov;
        }
    }
}

// ---------------------------------------------------------------------------
extern "C" void kernel_launch(void* const* d_in, const int* in_sizes, int n_in,
                              void* d_out, int out_size, void* d_ws, size_t ws_size,
                              hipStream_t stream) {
    (void)in_sizes; (void)n_in; (void)out_size; (void)ws_size;
    const int*   seq = (const int*)d_in[0];
    const float* h0  = (const float*)d_in[1];
    const float* enc = (const float*)d_in[2];
    const float* emb = (const float*)d_in[3];
    const float* Wih = (const float*)d_in[4];
    const float* Whh = (const float*)d_in[5];
    const float* bih = (const float*)d_in[6];
    const float* bhh = (const float*)d_in[7];
    const float* Wa  = (const float*)d_in[8];
    // d_in[9] = b_a: softmax over t is invariant to the per-b constant h·b_a -> unused
    const float* Wc  = (const float*)d_in[10];
    const float* bc  = (const float*)d_in[11];
    const float* Wo  = (const float*)d_in[12];
    const float* bo  = (const float*)d_in[13];

    float* out = (float*)d_out;
    float* hid = out + (size_t)B * V;

    float* ws   = (float*)d_ws;
    float* Pgi  = ws;                     // 786432
    float* Pgh  = Pgi + 786432;           // 786432
    float* Pu   = Pgh + 786432;           // 262144
    float* Pm   = Pu + 262144;            // 4096
    float* Pl   = Pm + 4096;              // 4096
    float* Pc   = Pl + 4096;              // 4194304 (16 MB)
    float* Pcg  = Pc + 4194304;           // 262144
    unsigned short* X_bf  = (unsigned short*)(Pcg + 262144);   // 65536 us
    unsigned short* h0_bf = X_bf + 65536;                      // 65536 us
    unsigned short* cat_bf = h0_bf + 65536;                    // 131072 us
    unsigned short* co_bf  = cat_bf + 131072;                  // 65536 us

    k_prep<<<256, 256, 0, stream>>>(seq, emb, h0, X_bf, h0_bf);
    // gates: z=0: Pgi = X @ Wih^T ; z=1: Pgh = h0 @ Whh^T   (split-K x4)
    k_mfma_bt<<<dim3(24, 4, 2), 256, 0, stream>>>(X_bf, h0_bf, H, Wih, Whh, H,
                                                  Pgi, Pgh, 3 * H, 256);
    k_gru<<<256, 256, 0, stream>>>(Pgi, Pgh, bih, bhh, h0, cat_bf, hid);
    k_mfma_wa<<<dim3(8, 4), 256, 0, stream>>>(cat_bf, Wa, Pu);
    k_flash<<<1024, 256, 0, stream>>>(Pu, enc, Pm, Pl, Pc);
    k_fcomb<<<64, 256, 0, stream>>>(Pm, Pl, Pc, cat_bf);
    // concat GEMM: Pcg = cat @ Wc^T   (K=2048, split-K x4, KC=512)
    k_mfma_bt<<<dim3(8, 4, 1), 256, 0, stream>>>(cat_bf, cat_bf, 2 * H, Wc, Wc, 2 * H,
                                                 Pcg, Pcg, H, 512);
    k_co<<<256, 256, 0, stream>>>(Pcg, bc, co_bf);
    k_out_mfma<<<(V + 127) / 128, 256, 0, stream>>>(co_bf, Wo, bo, out);
}

// Round 7
// 142.442 us; speedup vs baseline: 1.6402x; 1.1276x over previous
//
#include <hip/hip_runtime.h>
#include <hip/hip_bf16.h>
#include <cstdint>
#include <cstddef>

#define H 1024
#define V 50257
#define B 64
#define T 512

typedef __attribute__((ext_vector_type(8))) short bf16x8;
typedef __attribute__((ext_vector_type(4))) float f32x4;

__device__ __forceinline__ float sigmoidf_(float x) { return 1.0f / (1.0f + expf(-x)); }

__device__ __forceinline__ unsigned short f2bf_rn(float x) {
    __hip_bfloat16 h = __float2bfloat16(x);
    return __builtin_bit_cast(unsigned short, h);
}

__device__ __forceinline__ void gl_lds16(const float* g, float* l) {
    __builtin_amdgcn_global_load_lds(
        (const __attribute__((address_space(1))) unsigned*)g,
        (__attribute__((address_space(3))) unsigned*)l, 16, 0, 0);
}

// Per-wave wait: all my outstanding vmem (incl. global_load_lds) done.
// NOT a block barrier — used where each wave consumes only its own staged rows.
__device__ __forceinline__ void wave_vm_drain() {
    asm volatile("s_waitcnt vmcnt(0)" ::: "memory");
    __builtin_amdgcn_sched_barrier(0);
}

// ---------------------------------------------------------------------------
// Prep: X_bf = bf16(emb[seq]); h0_bf = bf16(h0)
__global__ void k_prep(const int* __restrict__ seq, const float* __restrict__ emb,
                       const float* __restrict__ h0,
                       unsigned short* __restrict__ X_bf,
                       unsigned short* __restrict__ h0_bf) {
    int i = blockIdx.x * 256 + threadIdx.x;   // 65536
    int b = i >> 10, h = i & 1023;
    X_bf[i] = f2bf_rn(emb[(size_t)seq[b] * H + h]);
    h0_bf[i] = f2bf_rn(h0[i]);
}

// ---------------------------------------------------------------------------
// Small-GEMM via bf16 MFMA, B row-major-in-K. C[m,n] = sum_k A[m,k]*Bm[n,k].
// M=64, BN=128, KC-chunk split-K. BARRIER-FREE: wave w stages and consumes
// only LDS rows [32w, 32w+32) -> per-wave vmcnt drain instead of syncthreads.
__global__ __launch_bounds__(256) void k_mfma_bt(
    const unsigned short* __restrict__ A0, const unsigned short* __restrict__ A1, int lda,
    const float* __restrict__ B0, const float* __restrict__ B1, int ldb,
    float* __restrict__ C0, float* __restrict__ C1, int N, int KC) {
    __shared__ __align__(16) float Bs[2][128 * 64];   // 32 KB x2
    const unsigned short* A = blockIdx.z ? A1 : A0;
    const float* Bm = blockIdx.z ? B1 : B0;
    float* C = (blockIdx.z ? C1 : C0) + (size_t)blockIdx.y * 64 * N;
    const int t = threadIdx.x;
    const int w = t >> 6, lane = t & 63;
    const int li = lane & 15, qu = lane >> 4;
    const int n0 = blockIdx.x * 128;
    const int k0 = blockIdx.y * KC;
    const int nsteps = KC >> 6;

    f32x4 acc[4][2];
#pragma unroll
    for (int ms = 0; ms < 4; ++ms)
#pragma unroll
        for (int nt = 0; nt < 2; ++nt) acc[ms][nt] = (f32x4){0.f, 0.f, 0.f, 0.f};

#define STG(BUF, KK)                                                            \
    {                                                                           \
        _Pragma("unroll")                                                       \
        for (int j = 0; j < 8; ++j) {                                           \
            int cidx = (w * 8 + j) * 64 + lane;                                 \
            int row = cidx >> 4, cs = cidx & 15;                                \
            int cg = cs ^ (row & 15);                                           \
            const float* gp = Bm + (size_t)(n0 + row) * ldb + (KK) + cg * 4;    \
            gl_lds16(gp, &Bs[BUF][(w * 8 + j) * 256]);                          \
        }                                                                       \
    }

    STG(0, k0)

    for (int kt = 0; kt < nsteps; ++kt) {
        const int buf = kt & 1;
        wave_vm_drain();                       // my buf-kt rows are in LDS
        if (kt + 1 < nsteps) STG(buf ^ 1, k0 + (kt + 1) * 64)

        const int kk = k0 + kt * 64;
#pragma unroll
        for (int ks = 0; ks < 2; ++ks) {
            bf16x8 af[4];
#pragma unroll
            for (int ms = 0; ms < 4; ++ms)
                af[ms] = *(const bf16x8*)&A[(size_t)(ms * 16 + li) * lda + kk + ks * 32 + qu * 8];
#pragma unroll
            for (int nt = 0; nt < 2; ++nt) {
                int row = w * 32 + nt * 16 + li;
                int cc0 = ks * 8 + qu * 2;
                float4 x0 = *(const float4*)&Bs[buf][row * 64 + ((cc0)     ^ (row & 15)) * 4];
                float4 x1 = *(const float4*)&Bs[buf][row * 64 + ((cc0 + 1) ^ (row & 15)) * 4];
                bf16x8 bfr;
                bfr[0] = (short)f2bf_rn(x0.x); bfr[1] = (short)f2bf_rn(x0.y);
                bfr[2] = (short)f2bf_rn(x0.z); bfr[3] = (short)f2bf_rn(x0.w);
                bfr[4] = (short)f2bf_rn(x1.x); bfr[5] = (short)f2bf_rn(x1.y);
                bfr[6] = (short)f2bf_rn(x1.z); bfr[7] = (short)f2bf_rn(x1.w);
#pragma unroll
                for (int ms = 0; ms < 4; ++ms)
                    acc[ms][nt] = __builtin_amdgcn_mfma_f32_16x16x32_bf16(
                        af[ms], bfr, acc[ms][nt], 0, 0, 0);
            }
        }
    }
#undef STG

#pragma unroll
    for (int nt = 0; nt < 2; ++nt) {
        int col = n0 + w * 32 + nt * 16 + li;
#pragma unroll
        for (int ms = 0; ms < 4; ++ms)
#pragma unroll
            for (int j = 0; j < 4; ++j)
                C[(size_t)(ms * 16 + qu * 4 + j) * N + col] = acc[ms][nt][j];
    }
}

// ---------------------------------------------------------------------------
// u-GEMM (B column-major-in-K): Pu[m,n] += sum_k h[m,k] * Wa[k,n].
__global__ __launch_bounds__(256) void k_mfma_wa(const unsigned short* __restrict__ cat_bf,
                                                 const float* __restrict__ Wa,
                                                 float* __restrict__ Pu) {
    const int t = threadIdx.x;
    const int w = t >> 6, lane = t & 63;
    const int li = lane & 15, qu = lane >> 4;
    const int n0 = blockIdx.x * 128;
    const int k0 = blockIdx.y * 256;

    f32x4 acc[4][2];
#pragma unroll
    for (int ms = 0; ms < 4; ++ms)
#pragma unroll
        for (int nt = 0; nt < 2; ++nt) acc[ms][nt] = (f32x4){0.f, 0.f, 0.f, 0.f};

    for (int kt = 0; kt < 4; ++kt) {
        const int kk = k0 + kt * 64;
#pragma unroll
        for (int ks = 0; ks < 2; ++ks) {
            bf16x8 af[4];
#pragma unroll
            for (int ms = 0; ms < 4; ++ms)
                af[ms] = *(const bf16x8*)&cat_bf[(size_t)(ms * 16 + li) * 2048 + kk + ks * 32 + qu * 8];
            const int kb = kk + ks * 32 + qu * 8;
#pragma unroll
            for (int nt = 0; nt < 2; ++nt) {
                int col = n0 + w * 32 + nt * 16 + li;
                bf16x8 bfr;
#pragma unroll
                for (int e = 0; e < 8; ++e)
                    bfr[e] = (short)f2bf_rn(Wa[(size_t)(kb + e) * H + col]);
#pragma unroll
                for (int ms = 0; ms < 4; ++ms)
                    acc[ms][nt] = __builtin_amdgcn_mfma_f32_16x16x32_bf16(
                        af[ms], bfr, acc[ms][nt], 0, 0, 0);
            }
        }
    }
    float* C = Pu + (size_t)blockIdx.y * 64 * H;
#pragma unroll
    for (int nt = 0; nt < 2; ++nt) {
        int col = n0 + w * 32 + nt * 16 + li;
#pragma unroll
        for (int ms = 0; ms < 4; ++ms)
#pragma unroll
            for (int j = 0; j < 4; ++j)
                C[(size_t)(ms * 16 + qu * 4 + j) * H + col] = acc[ms][nt][j];
    }
}

// ---------------------------------------------------------------------------
// GRU combine: fp32 partial sums -> h. Writes hid (fp32) and cat_bf[:, :H].
__global__ void k_gru(const float* __restrict__ Pgi, const float* __restrict__ Pgh,
                      const float* __restrict__ bih, const float* __restrict__ bhh,
                      const float* __restrict__ h0, unsigned short* __restrict__ cat_bf,
                      float* __restrict__ hid) {
    int i = blockIdx.x * 256 + threadIdx.x;   // 65536
    int b = i >> 10, h = i & 1023;
    float gr = bih[h], gz = bih[H + h], gn = bih[2 * H + h];
    float hr = bhh[h], hz = bhh[H + h], hn = bhh[2 * H + h];
#pragma unroll
    for (int kt = 0; kt < 4; ++kt) {
        const float* pi = Pgi + (size_t)kt * B * 3 * H + (size_t)b * 3 * H;
        const float* ph = Pgh + (size_t)kt * B * 3 * H + (size_t)b * 3 * H;
        gr += pi[h]; gz += pi[H + h]; gn += pi[2 * H + h];
        hr += ph[h]; hz += ph[H + h]; hn += ph[2 * H + h];
    }
    float r = sigmoidf_(gr + hr);
    float z = sigmoidf_(gz + hz);
    float n = tanhf(gn + r * hn);
    float hv = (1.0f - z) * n + z * h0[i];
    cat_bf[(size_t)b * 2048 + h] = f2bf_rn(hv);
    hid[i] = hv;
}

// ---------------------------------------------------------------------------
// Flash attention: block = (b, 32-row chunk), 4 waves x 8 rows. Online softmax
// per wave, 4-wave LDS combine -> 1024 partial records (4 MB).
__global__ __launch_bounds__(256) void k_flash(const float* __restrict__ Pu,
                                               const float* __restrict__ enc,
                                               float* __restrict__ Pm,
                                               float* __restrict__ Pl,
                                               float* __restrict__ Pc) {
    const int b = blockIdx.x >> 4, ch = blockIdx.x & 15;
    const int w = threadIdx.x >> 6, lane = threadIdx.x & 63;

    float4 uu[4];
#pragma unroll
    for (int it = 0; it < 4; ++it) {
        int col = (it * 64 + lane) * 4;
        float4 s = *(const float4*)&Pu[(size_t)b * H + col];
#pragma unroll
        for (int kt = 1; kt < 4; ++kt) {
            float4 p = *(const float4*)&Pu[(size_t)kt * B * H + (size_t)b * H + col];
            s.x += p.x; s.y += p.y; s.z += p.z; s.w += p.w;
        }
        uu[it] = s;
    }

    float m = -3.4e38f, l = 0.f;
    float4 c[4] = {{0,0,0,0},{0,0,0,0},{0,0,0,0},{0,0,0,0}};
    const float* ebase = enc + ((size_t)b * T + ch * 32 + w * 8) * H;

#pragma unroll 2
    for (int tt = 0; tt < 8; ++tt) {
        float4 e[4];
#pragma unroll
        for (int it = 0; it < 4; ++it)
            e[it] = *(const float4*)&ebase[(size_t)tt * H + (it * 64 + lane) * 4];
        float s = 0.f;
#pragma unroll
        for (int it = 0; it < 4; ++it)
            s += uu[it].x * e[it].x + uu[it].y * e[it].y +
                 uu[it].z * e[it].z + uu[it].w * e[it].w;
#pragma unroll
        for (int o = 32; o; o >>= 1) s += __shfl_xor(s, o, 64);
        float mn = fmaxf(m, s);
        float scale = __expf(m - mn);
        float p = __expf(s - mn);
        l = l * scale + p;
#pragma unroll
        for (int it = 0; it < 4; ++it) {
            c[it].x = fmaf(p, e[it].x, c[it].x * scale);
            c[it].y = fmaf(p, e[it].y, c[it].y * scale);
            c[it].z = fmaf(p, e[it].z, c[it].z * scale);
            c[it].w = fmaf(p, e[it].w, c[it].w * scale);
        }
        m = mn;
    }

    __shared__ float Lm[4], Ll[4];
    __shared__ __align__(16) float Lc[4][H];
#pragma unroll
    for (int it = 0; it < 4; ++it)
        *(float4*)&Lc[w][(it * 64 + lane) * 4] = c[it];
    if (lane == 0) { Lm[w] = m; Ll[w] = l; }
    __syncthreads();

    float M = fmaxf(fmaxf(Lm[0], Lm[1]), fmaxf(Lm[2], Lm[3]));
    float e0 = __expf(Lm[0] - M), e1 = __expf(Lm[1] - M),
          e2 = __expf(Lm[2] - M), e3 = __expf(Lm[3] - M);
    float L = Ll[0] * e0 + Ll[1] * e1 + Ll[2] * e2 + Ll[3] * e3;
    int col = threadIdx.x * 4;
    float4 c0 = *(const float4*)&Lc[0][col];
    float4 c1 = *(const float4*)&Lc[1][col];
    float4 c2 = *(const float4*)&Lc[2][col];
    float4 c3 = *(const float4*)&Lc[3][col];
    float4 cc;
    cc.x = c0.x * e0 + c1.x * e1 + c2.x * e2 + c3.x * e3;
    cc.y = c0.y * e0 + c1.y * e1 + c2.y * e2 + c3.y * e3;
    cc.z = c0.z * e0 + c1.z * e1 + c2.z * e2 + c3.z * e3;
    cc.w = c0.w * e0 + c1.w * e1 + c2.w * e2 + c3.w * e3;
    const int rec = blockIdx.x;   // b*16 + ch
    if (threadIdx.x == 0) { Pm[rec] = M; Pl[rec] = L; }
    *(float4*)&Pc[(size_t)rec * H + col] = cc;
}

// Combine 16 chunk-partials per b -> context -> cat_bf[:, H:2H]
__global__ void k_fcomb(const float* __restrict__ Pm, const float* __restrict__ Pl,
                        const float* __restrict__ Pc, unsigned short* __restrict__ cat_bf) {
    const int b = blockIdx.x;
    const int col = threadIdx.x * 4;
    float M = -3.4e38f;
#pragma unroll
    for (int i = 0; i < 16; ++i) M = fmaxf(M, Pm[b * 16 + i]);
    float L = 0.f;
    float4 cc = {0, 0, 0, 0};
#pragma unroll 4
    for (int i = 0; i < 16; ++i) {
        float wgt = __expf(Pm[b * 16 + i] - M);
        L += Pl[b * 16 + i] * wgt;
        float4 p = *(const float4*)&Pc[(size_t)(b * 16 + i) * H + col];
        cc.x += wgt * p.x; cc.y += wgt * p.y;
        cc.z += wgt * p.z; cc.w += wgt * p.w;
    }
    float inv = 1.0f / L;
    ushort4 o;
    o.x = f2bf_rn(cc.x * inv); o.y = f2bf_rn(cc.y * inv);
    o.z = f2bf_rn(cc.z * inv); o.w = f2bf_rn(cc.w * inv);
    *(ushort4*)&cat_bf[(size_t)b * 2048 + 1024 + col] = o;
}

// co = tanh(sum partials + b_c), written as bf16
__global__ void k_co(const float* __restrict__ Pc, const float* __restrict__ bc,
                     unsigned short* __restrict__ co_bf) {
    int i = blockIdx.x * 256 + threadIdx.x;
    int h = i & 1023;
    float s = bc[h];
#pragma unroll
    for (int kt = 0; kt < 4; ++kt) s += Pc[kt * (B * H) + i];
    co_bf[i] = f2bf_rn(tanhf(s));
}

// ---------------------------------------------------------------------------
// Output GEMM: out[b,v] = sum_h co[b,h]*Wo[v,h] + bo[v].  BN=128, BK=64.
// BARRIER-FREE (wave-private LDS rows) + per-wave vmcnt drain: waves free-run,
// no block-wide vmcnt(0) drain, HBM queue never empties.
__global__ __launch_bounds__(256) void k_out_mfma(const unsigned short* __restrict__ co_bf,
                                                  const float* __restrict__ Wo,
                                                  const float* __restrict__ bo,
                                                  float* __restrict__ out) {
    __shared__ __align__(16) float Bs[2][128 * 64];   // 32 KB x2
    const int t = threadIdx.x;
    const int w = t >> 6, lane = t & 63;
    const int li = lane & 15, qu = lane >> 4;
    const int v0 = blockIdx.x * 128;

    f32x4 acc[4][2];
#pragma unroll
    for (int ms = 0; ms < 4; ++ms)
#pragma unroll
        for (int nt = 0; nt < 2; ++nt) acc[ms][nt] = (f32x4){0.f, 0.f, 0.f, 0.f};

#define STAGE(BUF, KK)                                                          \
    {                                                                           \
        _Pragma("unroll")                                                       \
        for (int j = 0; j < 8; ++j) {                                           \
            int cidx = (w * 8 + j) * 64 + lane;                                 \
            int row = cidx >> 4, cs = cidx & 15;                                \
            int cg = cs ^ (row & 15);                                           \
            int vr = v0 + row; if (vr >= V) vr = V - 1;                         \
            const float* gp = Wo + (size_t)vr * H + (KK) + cg * 4;              \
            gl_lds16(gp, &Bs[BUF][(w * 8 + j) * 256]);                          \
        }                                                                       \
    }

    STAGE(0, 0)

    for (int kt = 0; kt < 16; ++kt) {
        const int buf = kt & 1;
        wave_vm_drain();                       // my buf-kt rows landed
        if (kt < 15) STAGE(buf ^ 1, (kt + 1) * 64)

        const int kk = kt * 64;
#pragma unroll
        for (int ks = 0; ks < 2; ++ks) {
            bf16x8 af[4];
#pragma unroll
            for (int ms = 0; ms < 4; ++ms)
                af[ms] = *(const bf16x8*)&co_bf[(size_t)(ms * 16 + li) * H + kk + ks * 32 + qu * 8];
#pragma unroll
            for (int nt = 0; nt < 2; ++nt) {
                int row = w * 32 + nt * 16 + li;
                int cc0 = ks * 8 + qu * 2;
                float4 x0 = *(const float4*)&Bs[buf][row * 64 + ((cc0)     ^ (row & 15)) * 4];
                float4 x1 = *(const float4*)&Bs[buf][row * 64 + ((cc0 + 1) ^ (row & 15)) * 4];
                bf16x8 bfr;
                bfr[0] = (short)f2bf_rn(x0.x); bfr[1] = (short)f2bf_rn(x0.y);
                bfr[2] = (short)f2bf_rn(x0.z); bfr[3] = (short)f2bf_rn(x0.w);
                bfr[4] = (short)f2bf_rn(x1.x); bfr[5] = (short)f2bf_rn(x1.y);
                bfr[6] = (short)f2bf_rn(x1.z); bfr[7] = (short)f2bf_rn(x1.w);
#pragma unroll
                for (int ms = 0; ms < 4; ++ms)
                    acc[ms][nt] = __builtin_amdgcn_mfma_f32_16x16x32_bf16(
                        af[ms], bfr, acc[ms][nt], 0, 0, 0);
            }
        }
    }
#undef STAGE

#pragma unroll
    for (int nt = 0; nt < 2; ++nt) {
        int v = v0 + w * 32 + nt * 16 + li;
        if (v < V) {
            float bov = bo[v];
#pragma unroll
            for (int ms = 0; ms < 4; ++ms)
#pragma unroll
                for (int j = 0; j < 4; ++j)
                    out[(size_t)(ms * 16 + qu * 4 + j) * V + v] = acc[ms][nt][j] + bov;
        }
    }
}

// ---------------------------------------------------------------------------
extern "C" void kernel_launch(void* const* d_in, const int* in_sizes, int n_in,
                              void* d_out, int out_size, void* d_ws, size_t ws_size,
                              hipStream_t stream) {
    (void)in_sizes; (void)n_in; (void)out_size; (void)ws_size;
    const int*   seq = (const int*)d_in[0];
    const float* h0  = (const float*)d_in[1];
    const float* enc = (const float*)d_in[2];
    const float* emb = (const float*)d_in[3];
    const float* Wih = (const float*)d_in[4];
    const float* Whh = (const float*)d_in[5];
    const float* bih = (const float*)d_in[6];
    const float* bhh = (const float*)d_in[7];
    const float* Wa  = (const float*)d_in[8];
    // d_in[9] = b_a: softmax over t is invariant to the per-b constant h·b_a -> unused
    const float* Wc  = (const float*)d_in[10];
    const float* bc  = (const float*)d_in[11];
    const float* Wo  = (const float*)d_in[12];
    const float* bo  = (const float*)d_in[13];

    float* out = (float*)d_out;
    float* hid = out + (size_t)B * V;

    float* ws   = (float*)d_ws;
    float* Pgi  = ws;                     // 786432
    float* Pgh  = Pgi + 786432;           // 786432
    float* Pu   = Pgh + 786432;           // 262144
    float* Pm   = Pu + 262144;            // 1024
    float* Pl   = Pm + 1024;              // 1024
    float* Pc   = Pl + 1024;              // 1048576 (4 MB)
    float* Pcg  = Pc + 1048576;           // 262144
    unsigned short* X_bf  = (unsigned short*)(Pcg + 262144);   // 65536 us
    unsigned short* h0_bf = X_bf + 65536;                      // 65536 us
    unsigned short* cat_bf = h0_bf + 65536;                    // 131072 us
    unsigned short* co_bf  = cat_bf + 131072;                  // 65536 us

    k_prep<<<256, 256, 0, stream>>>(seq, emb, h0, X_bf, h0_bf);
    k_mfma_bt<<<dim3(24, 4, 2), 256, 0, stream>>>(X_bf, h0_bf, H, Wih, Whh, H,
                                                  Pgi, Pgh, 3 * H, 256);
    k_gru<<<256, 256, 0, stream>>>(Pgi, Pgh, bih, bhh, h0, cat_bf, hid);
    k_mfma_wa<<<dim3(8, 4), 256, 0, stream>>>(cat_bf, Wa, Pu);
    k_flash<<<1024, 256, 0, stream>>>(Pu, enc, Pm, Pl, Pc);
    k_fcomb<<<64, 256, 0, stream>>>(Pm, Pl, Pc, cat_bf);
    k_mfma_bt<<<dim3(8, 4, 1), 256, 0, stream>>>(cat_bf, cat_bf, 2 * H, Wc, Wc, 2 * H,
                                                 Pcg, Pcg, H, 512);
    k_co<<<256, 256, 0, stream>>>(Pcg, bc, co_bf);
    k_out_mfma<<<(V + 127) / 128, 256, 0, stream>>>(co_bf, Wo, bo, out);
}

// Round 8
// 142.437 us; speedup vs baseline: 1.6403x; 1.0000x over previous
//
#include <hip/hip_runtime.h>
#include <hip/hip_bf16.h>
#include <cstdint>
#include <cstddef>

#define H 1024
#define V 50257
#define B 64
#define T 512

typedef __attribute__((ext_vector_type(8))) short bf16x8;
typedef __attribute__((ext_vector_type(4))) float f32x4;

__device__ __forceinline__ float sigmoidf_(float x) { return 1.0f / (1.0f + expf(-x)); }

__device__ __forceinline__ unsigned short f2bf_rn(float x) {
    __hip_bfloat16 h = __float2bfloat16(x);
    return __builtin_bit_cast(unsigned short, h);
}

__device__ __forceinline__ void gl_lds16(const float* g, float* l) {
    __builtin_amdgcn_global_load_lds(
        (const __attribute__((address_space(1))) unsigned*)g,
        (__attribute__((address_space(3))) unsigned*)l, 16, 0, 0);
}

// Counted per-wave waits (barrier-free pipeline). sched_barrier pins motion.
__device__ __forceinline__ void wait_vm8() {
    asm volatile("s_waitcnt vmcnt(8)" ::: "memory");
    __builtin_amdgcn_sched_barrier(0);
}
__device__ __forceinline__ void wait_vm0() {
    asm volatile("s_waitcnt vmcnt(0)" ::: "memory");
    __builtin_amdgcn_sched_barrier(0);
}
// Guard before re-staging into the buffer consumed this iteration (WAR on LDS).
__device__ __forceinline__ void lds_war_guard() {
    asm volatile("s_waitcnt lgkmcnt(0)" ::: "memory");
    __builtin_amdgcn_sched_barrier(0);
}

// ---------------------------------------------------------------------------
// Gate GEMMs (k_prep folded in): z=0: Pgi = bf16(emb[seq]) @ Wih^T ;
// z=1: Pgh = bf16(h0) @ Whh^T.  M=64, BN=128, split-K (KC=256, grid.y=4).
// Barrier-free wave-private LDS rows + 2-ahead counted-vmcnt staging.
__global__ __launch_bounds__(256) void k_gates(const int* __restrict__ seq,
                                               const float* __restrict__ emb,
                                               const float* __restrict__ h0,
                                               const float* __restrict__ Wih,
                                               const float* __restrict__ Whh,
                                               float* __restrict__ Pgi,
                                               float* __restrict__ Pgh) {
    __shared__ __align__(16) float Bs[2][128 * 64];   // 32 KB x2
    const int z = blockIdx.z;
    const float* Bm = z ? Whh : Wih;
    float* C = (z ? Pgh : Pgi) + (size_t)blockIdx.y * 64 * (3 * H);
    const int t = threadIdx.x;
    const int w = t >> 6, lane = t & 63;
    const int li = lane & 15, qu = lane >> 4;
    const int n0 = blockIdx.x * 128;
    const int k0 = blockIdx.y * 256;
    const int N = 3 * H;

    const float* Arow[4];
#pragma unroll
    for (int ms = 0; ms < 4; ++ms) {
        int m = ms * 16 + li;
        Arow[ms] = z ? (h0 + (size_t)m * H) : (emb + (size_t)seq[m] * H);
    }

    f32x4 acc[4][2];
#pragma unroll
    for (int ms = 0; ms < 4; ++ms)
#pragma unroll
        for (int nt = 0; nt < 2; ++nt) acc[ms][nt] = (f32x4){0.f, 0.f, 0.f, 0.f};

#define STG(BUF, KK)                                                            \
    {                                                                           \
        _Pragma("unroll")                                                       \
        for (int j = 0; j < 8; ++j) {                                           \
            int cidx = (w * 8 + j) * 64 + lane;                                 \
            int row = cidx >> 4, cs = cidx & 15;                                \
            int cg = cs ^ (row & 15);                                           \
            const float* gp = Bm + (size_t)(n0 + row) * H + (KK) + cg * 4;      \
            gl_lds16(gp, &Bs[BUF][(w * 8 + j) * 256]);                          \
        }                                                                       \
    }

#define CONSUME(BUF, KK)                                                        \
    {                                                                           \
        _Pragma("unroll")                                                       \
        for (int ks = 0; ks < 2; ++ks) {                                        \
            bf16x8 af[4];                                                       \
            _Pragma("unroll")                                                   \
            for (int ms = 0; ms < 4; ++ms) {                                    \
                float4 a0 = *(const float4*)&Arow[ms][(KK) + ks * 32 + qu * 8]; \
                float4 a1 = *(const float4*)&Arow[ms][(KK) + ks * 32 + qu * 8 + 4]; \
                af[ms][0] = (short)f2bf_rn(a0.x); af[ms][1] = (short)f2bf_rn(a0.y); \
                af[ms][2] = (short)f2bf_rn(a0.z); af[ms][3] = (short)f2bf_rn(a0.w); \
                af[ms][4] = (short)f2bf_rn(a1.x); af[ms][5] = (short)f2bf_rn(a1.y); \
                af[ms][6] = (short)f2bf_rn(a1.z); af[ms][7] = (short)f2bf_rn(a1.w); \
            }                                                                   \
            _Pragma("unroll")                                                   \
            for (int nt = 0; nt < 2; ++nt) {                                    \
                int row = w * 32 + nt * 16 + li;                                \
                int cc0 = ks * 8 + qu * 2;                                      \
                float4 x0 = *(const float4*)&Bs[BUF][row * 64 + ((cc0)     ^ (row & 15)) * 4]; \
                float4 x1 = *(const float4*)&Bs[BUF][row * 64 + ((cc0 + 1) ^ (row & 15)) * 4]; \
                bf16x8 bfr;                                                     \
                bfr[0] = (short)f2bf_rn(x0.x); bfr[1] = (short)f2bf_rn(x0.y);   \
                bfr[2] = (short)f2bf_rn(x0.z); bfr[3] = (short)f2bf_rn(x0.w);   \
                bfr[4] = (short)f2bf_rn(x1.x); bfr[5] = (short)f2bf_rn(x1.y);   \
                bfr[6] = (short)f2bf_rn(x1.z); bfr[7] = (short)f2bf_rn(x1.w);   \
                _Pragma("unroll")                                               \
                for (int ms = 0; ms < 4; ++ms)                                  \
                    acc[ms][nt] = __builtin_amdgcn_mfma_f32_16x16x32_bf16(      \
                        af[ms], bfr, acc[ms][nt], 0, 0, 0);                     \
            }                                                                   \
        }                                                                       \
    }

    STG(0, k0)
    STG(1, k0 + 64)
    for (int kt = 0; kt < 3; ++kt) {
        const int buf = kt & 1;
        wait_vm8();
        CONSUME(buf, k0 + kt * 64)
        if (kt + 2 < 4) { lds_war_guard(); STG(buf, k0 + (kt + 2) * 64) }
    }
    wait_vm0();
    CONSUME(1, k0 + 3 * 64)
#undef STG
#undef CONSUME

#pragma unroll
    for (int nt = 0; nt < 2; ++nt) {
        int col = n0 + w * 32 + nt * 16 + li;
#pragma unroll
        for (int ms = 0; ms < 4; ++ms)
#pragma unroll
            for (int j = 0; j < 4; ++j)
                C[(size_t)(ms * 16 + qu * 4 + j) * N + col] = acc[ms][nt][j];
    }
}

// ---------------------------------------------------------------------------
// Wc GEMM via bf16 MFMA, B row-major-in-K. C[m,n] = sum_k A[m,k]*Bm[n,k].
// Barrier-free + 2-ahead counted vmcnt.  nsteps = KC/64 (>=2).
__global__ __launch_bounds__(256) void k_mfma_bt(const unsigned short* __restrict__ A,
                                                 int lda,
                                                 const float* __restrict__ Bm, int ldb,
                                                 float* __restrict__ Cp, int N, int KC) {
    __shared__ __align__(16) float Bs[2][128 * 64];   // 32 KB x2
    float* C = Cp + (size_t)blockIdx.y * 64 * N;
    const int t = threadIdx.x;
    const int w = t >> 6, lane = t & 63;
    const int li = lane & 15, qu = lane >> 4;
    const int n0 = blockIdx.x * 128;
    const int k0 = blockIdx.y * KC;
    const int nsteps = KC >> 6;

    f32x4 acc[4][2];
#pragma unroll
    for (int ms = 0; ms < 4; ++ms)
#pragma unroll
        for (int nt = 0; nt < 2; ++nt) acc[ms][nt] = (f32x4){0.f, 0.f, 0.f, 0.f};

#define STG(BUF, KK)                                                            \
    {                                                                           \
        _Pragma("unroll")                                                       \
        for (int j = 0; j < 8; ++j) {                                           \
            int cidx = (w * 8 + j) * 64 + lane;                                 \
            int row = cidx >> 4, cs = cidx & 15;                                \
            int cg = cs ^ (row & 15);                                           \
            const float* gp = Bm + (size_t)(n0 + row) * ldb + (KK) + cg * 4;    \
            gl_lds16(gp, &Bs[BUF][(w * 8 + j) * 256]);                          \
        }                                                                       \
    }

#define CONSUME(BUF, KK)                                                        \
    {                                                                           \
        _Pragma("unroll")                                                       \
        for (int ks = 0; ks < 2; ++ks) {                                        \
            bf16x8 af[4];                                                       \
            _Pragma("unroll")                                                   \
            for (int ms = 0; ms < 4; ++ms)                                      \
                af[ms] = *(const bf16x8*)&A[(size_t)(ms * 16 + li) * lda + (KK) + ks * 32 + qu * 8]; \
            _Pragma("unroll")                                                   \
            for (int nt = 0; nt < 2; ++nt) {                                    \
                int row = w * 32 + nt * 16 + li;                                \
                int cc0 = ks * 8 + qu * 2;                                      \
                float4 x0 = *(const float4*)&Bs[BUF][row * 64 + ((cc0)     ^ (row & 15)) * 4]; \
                float4 x1 = *(const float4*)&Bs[BUF][row * 64 + ((cc0 + 1) ^ (row & 15)) * 4]; \
                bf16x8 bfr;                                                     \
                bfr[0] = (short)f2bf_rn(x0.x); bfr[1] = (short)f2bf_rn(x0.y);   \
                bfr[2] = (short)f2bf_rn(x0.z); bfr[3] = (short)f2bf_rn(x0.w);   \
                bfr[4] = (short)f2bf_rn(x1.x); bfr[5] = (short)f2bf_rn(x1.y);   \
                bfr[6] = (short)f2bf_rn(x1.z); bfr[7] = (short)f2bf_rn(x1.w);   \
                _Pragma("unroll")                                               \
                for (int ms = 0; ms < 4; ++ms)                                  \
                    acc[ms][nt] = __builtin_amdgcn_mfma_f32_16x16x32_bf16(      \
                        af[ms], bfr, acc[ms][nt], 0, 0, 0);                     \
            }                                                                   \
        }                                                                       \
    }

    STG(0, k0)
    STG(1, k0 + 64)
    for (int kt = 0; kt < nsteps - 1; ++kt) {
        const int buf = kt & 1;
        wait_vm8();
        CONSUME(buf, k0 + kt * 64)
        if (kt + 2 < nsteps) { lds_war_guard(); STG(buf, k0 + (kt + 2) * 64) }
    }
    wait_vm0();
    CONSUME((nsteps - 1) & 1, k0 + (nsteps - 1) * 64)
#undef STG
#undef CONSUME

#pragma unroll
    for (int nt = 0; nt < 2; ++nt) {
        int col = n0 + w * 32 + nt * 16 + li;
#pragma unroll
        for (int ms = 0; ms < 4; ++ms)
#pragma unroll
            for (int j = 0; j < 4; ++j)
                C[(size_t)(ms * 16 + qu * 4 + j) * N + col] = acc[ms][nt][j];
    }
}

// ---------------------------------------------------------------------------
// u-GEMM (B column-major-in-K): Pu[m,n] += sum_k h[m,k] * Wa[k,n].
__global__ __launch_bounds__(256) void k_mfma_wa(const unsigned short* __restrict__ cat_bf,
                                                 const float* __restrict__ Wa,
                                                 float* __restrict__ Pu) {
    const int t = threadIdx.x;
    const int w = t >> 6, lane = t & 63;
    const int li = lane & 15, qu = lane >> 4;
    const int n0 = blockIdx.x * 128;
    const int k0 = blockIdx.y * 256;

    f32x4 acc[4][2];
#pragma unroll
    for (int ms = 0; ms < 4; ++ms)
#pragma unroll
        for (int nt = 0; nt < 2; ++nt) acc[ms][nt] = (f32x4){0.f, 0.f, 0.f, 0.f};

    for (int kt = 0; kt < 4; ++kt) {
        const int kk = k0 + kt * 64;
#pragma unroll
        for (int ks = 0; ks < 2; ++ks) {
            bf16x8 af[4];
#pragma unroll
            for (int ms = 0; ms < 4; ++ms)
                af[ms] = *(const bf16x8*)&cat_bf[(size_t)(ms * 16 + li) * 2048 + kk + ks * 32 + qu * 8];
            const int kb = kk + ks * 32 + qu * 8;
#pragma unroll
            for (int nt = 0; nt < 2; ++nt) {
                int col = n0 + w * 32 + nt * 16 + li;
                bf16x8 bfr;
#pragma unroll
                for (int e = 0; e < 8; ++e)
                    bfr[e] = (short)f2bf_rn(Wa[(size_t)(kb + e) * H + col]);
#pragma unroll
                for (int ms = 0; ms < 4; ++ms)
                    acc[ms][nt] = __builtin_amdgcn_mfma_f32_16x16x32_bf16(
                        af[ms], bfr, acc[ms][nt], 0, 0, 0);
            }
        }
    }
    float* C = Pu + (size_t)blockIdx.y * 64 * H;
#pragma unroll
    for (int nt = 0; nt < 2; ++nt) {
        int col = n0 + w * 32 + nt * 16 + li;
#pragma unroll
        for (int ms = 0; ms < 4; ++ms)
#pragma unroll
            for (int j = 0; j < 4; ++j)
                C[(size_t)(ms * 16 + qu * 4 + j) * H + col] = acc[ms][nt][j];
    }
}

// ---------------------------------------------------------------------------
// GRU combine: fp32 partial sums -> h. Writes hid (fp32) and cat_bf[:, :H].
__global__ void k_gru(const float* __restrict__ Pgi, const float* __restrict__ Pgh,
                      const float* __restrict__ bih, const float* __restrict__ bhh,
                      const float* __restrict__ h0, unsigned short* __restrict__ cat_bf,
                      float* __restrict__ hid) {
    int i = blockIdx.x * 256 + threadIdx.x;   // 65536
    int b = i >> 10, h = i & 1023;
    float gr = bih[h], gz = bih[H + h], gn = bih[2 * H + h];
    float hr = bhh[h], hz = bhh[H + h], hn = bhh[2 * H + h];
#pragma unroll
    for (int kt = 0; kt < 4; ++kt) {
        const float* pi = Pgi + (size_t)kt * B * 3 * H + (size_t)b * 3 * H;
        const float* ph = Pgh + (size_t)kt * B * 3 * H + (size_t)b * 3 * H;
        gr += pi[h]; gz += pi[H + h]; gn += pi[2 * H + h];
        hr += ph[h]; hz += ph[H + h]; hn += ph[2 * H + h];
    }
    float r = sigmoidf_(gr + hr);
    float z = sigmoidf_(gz + hz);
    float n = tanhf(gn + r * hn);
    float hv = (1.0f - z) * n + z * h0[i];
    cat_bf[(size_t)b * 2048 + h] = f2bf_rn(hv);
    hid[i] = hv;
}

// ---------------------------------------------------------------------------
// Flash attention: block = (b, 32-row chunk), 4 waves x 8 rows. Online softmax
// per wave, 4-wave LDS combine -> 1024 partial records (4 MB).
__global__ __launch_bounds__(256) void k_flash(const float* __restrict__ Pu,
                                               const float* __restrict__ enc,
                                               float* __restrict__ Pm,
                                               float* __restrict__ Pl,
                                               float* __restrict__ Pc) {
    const int b = blockIdx.x >> 4, ch = blockIdx.x & 15;
    const int w = threadIdx.x >> 6, lane = threadIdx.x & 63;

    float4 uu[4];
#pragma unroll
    for (int it = 0; it < 4; ++it) {
        int col = (it * 64 + lane) * 4;
        float4 s = *(const float4*)&Pu[(size_t)b * H + col];
#pragma unroll
        for (int kt = 1; kt < 4; ++kt) {
            float4 p = *(const float4*)&Pu[(size_t)kt * B * H + (size_t)b * H + col];
            s.x += p.x; s.y += p.y; s.z += p.z; s.w += p.w;
        }
        uu[it] = s;
    }

    float m = -3.4e38f, l = 0.f;
    float4 c[4] = {{0,0,0,0},{0,0,0,0},{0,0,0,0},{0,0,0,0}};
    const float* ebase = enc + ((size_t)b * T + ch * 32 + w * 8) * H;

#pragma unroll 2
    for (int tt = 0; tt < 8; ++tt) {
        float4 e[4];
#pragma unroll
        for (int it = 0; it < 4; ++it)
            e[it] = *(const float4*)&ebase[(size_t)tt * H + (it * 64 + lane) * 4];
        float s = 0.f;
#pragma unroll
        for (int it = 0; it < 4; ++it)
            s += uu[it].x * e[it].x + uu[it].y * e[it].y +
                 uu[it].z * e[it].z + uu[it].w * e[it].w;
#pragma unroll
        for (int o = 32; o; o >>= 1) s += __shfl_xor(s, o, 64);
        float mn = fmaxf(m, s);
        float scale = __expf(m - mn);
        float p = __expf(s - mn);
        l = l * scale + p;
#pragma unroll
        for (int it = 0; it < 4; ++it) {
            c[it].x = fmaf(p, e[it].x, c[it].x * scale);
            c[it].y = fmaf(p, e[it].y, c[it].y * scale);
            c[it].z = fmaf(p, e[it].z, c[it].z * scale);
            c[it].w = fmaf(p, e[it].w, c[it].w * scale);
        }
        m = mn;
    }

    __shared__ float Lm[4], Ll[4];
    __shared__ __align__(16) float Lc[4][H];
#pragma unroll
    for (int it = 0; it < 4; ++it)
        *(float4*)&Lc[w][(it * 64 + lane) * 4] = c[it];
    if (lane == 0) { Lm[w] = m; Ll[w] = l; }
    __syncthreads();

    float M = fmaxf(fmaxf(Lm[0], Lm[1]), fmaxf(Lm[2], Lm[3]));
    float e0 = __expf(Lm[0] - M), e1 = __expf(Lm[1] - M),
          e2 = __expf(Lm[2] - M), e3 = __expf(Lm[3] - M);
    float L = Ll[0] * e0 + Ll[1] * e1 + Ll[2] * e2 + Ll[3] * e3;
    int col = threadIdx.x * 4;
    float4 c0 = *(const float4*)&Lc[0][col];
    float4 c1 = *(const float4*)&Lc[1][col];
    float4 c2 = *(const float4*)&Lc[2][col];
    float4 c3 = *(const float4*)&Lc[3][col];
    float4 cc;
    cc.x = c0.x * e0 + c1.x * e1 + c2.x * e2 + c3.x * e3;
    cc.y = c0.y * e0 + c1.y * e1 + c2.y * e2 + c3.y * e3;
    cc.z = c0.z * e0 + c1.z * e1 + c2.z * e2 + c3.z * e3;
    cc.w = c0.w * e0 + c1.w * e1 + c2.w * e2 + c3.w * e3;
    const int rec = blockIdx.x;   // b*16 + ch
    if (threadIdx.x == 0) { Pm[rec] = M; Pl[rec] = L; }
    *(float4*)&Pc[(size_t)rec * H + col] = cc;
}

// Combine 16 chunk-partials per b -> context -> cat_bf[:, H:2H]
__global__ void k_fcomb(const float* __restrict__ Pm, const float* __restrict__ Pl,
                        const float* __restrict__ Pc, unsigned short* __restrict__ cat_bf) {
    const int b = blockIdx.x;
    const int col = threadIdx.x * 4;
    float M = -3.4e38f;
#pragma unroll
    for (int i = 0; i < 16; ++i) M = fmaxf(M, Pm[b * 16 + i]);
    float L = 0.f;
    float4 cc = {0, 0, 0, 0};
#pragma unroll 4
    for (int i = 0; i < 16; ++i) {
        float wgt = __expf(Pm[b * 16 + i] - M);
        L += Pl[b * 16 + i] * wgt;
        float4 p = *(const float4*)&Pc[(size_t)(b * 16 + i) * H + col];
        cc.x += wgt * p.x; cc.y += wgt * p.y;
        cc.z += wgt * p.z; cc.w += wgt * p.w;
    }
    float inv = 1.0f / L;
    ushort4 o;
    o.x = f2bf_rn(cc.x * inv); o.y = f2bf_rn(cc.y * inv);
    o.z = f2bf_rn(cc.z * inv); o.w = f2bf_rn(cc.w * inv);
    *(ushort4*)&cat_bf[(size_t)b * 2048 + 1024 + col] = o;
}

// co = tanh(sum partials + b_c), written as bf16
__global__ void k_co(const float* __restrict__ Pc, const float* __restrict__ bc,
                     unsigned short* __restrict__ co_bf) {
    int i = blockIdx.x * 256 + threadIdx.x;
    int h = i & 1023;
    float s = bc[h];
#pragma unroll
    for (int kt = 0; kt < 4; ++kt) s += Pc[kt * (B * H) + i];
    co_bf[i] = f2bf_rn(tanhf(s));
}

// ---------------------------------------------------------------------------
// Output GEMM: out[b,v] = sum_h co[b,h]*Wo[v,h] + bo[v].  BN=128, BK=64.
// Barrier-free wave-private LDS rows + 2-ahead counted-vmcnt staging: per-wave
// outstanding never drops to 0; each stage has ~2 consume-phases to land.
__global__ __launch_bounds__(256) void k_out_mfma(const unsigned short* __restrict__ co_bf,
                                                  const float* __restrict__ Wo,
                                                  const float* __restrict__ bo,
                                                  float* __restrict__ out) {
    __shared__ __align__(16) float Bs[2][128 * 64];   // 32 KB x2
    const int t = threadIdx.x;
    const int w = t >> 6, lane = t & 63;
    const int li = lane & 15, qu = lane >> 4;
    const int v0 = blockIdx.x * 128;

    f32x4 acc[4][2];
#pragma unroll
    for (int ms = 0; ms < 4; ++ms)
#pragma unroll
        for (int nt = 0; nt < 2; ++nt) acc[ms][nt] = (f32x4){0.f, 0.f, 0.f, 0.f};

#define STAGE(BUF, KK)                                                          \
    {                                                                           \
        _Pragma("unroll")                                                       \
        for (int j = 0; j < 8; ++j) {                                           \
            int cidx = (w * 8 + j) * 64 + lane;                                 \
            int row = cidx >> 4, cs = cidx & 15;                                \
            int cg = cs ^ (row & 15);                                           \
            int vr = v0 + row; if (vr >= V) vr = V - 1;                         \
            const float* gp = Wo + (size_t)vr * H + (KK) + cg * 4;              \
            gl_lds16(gp, &Bs[BUF][(w * 8 + j) * 256]);                          \
        }                                                                       \
    }

#define CONSUME(BUF, KK)                                                        \
    {                                                                           \
        _Pragma("unroll")                                                       \
        for (int ks = 0; ks < 2; ++ks) {                                        \
            bf16x8 af[4];                                                       \
            _Pragma("unroll")                                                   \
            for (int ms = 0; ms < 4; ++ms)                                      \
                af[ms] = *(const bf16x8*)&co_bf[(size_t)(ms * 16 + li) * H + (KK) + ks * 32 + qu * 8]; \
            _Pragma("unroll")                                                   \
            for (int nt = 0; nt < 2; ++nt) {                                    \
                int row = w * 32 + nt * 16 + li;                                \
                int cc0 = ks * 8 + qu * 2;                                      \
                float4 x0 = *(const float4*)&Bs[BUF][row * 64 + ((cc0)     ^ (row & 15)) * 4]; \
                float4 x1 = *(const float4*)&Bs[BUF][row * 64 + ((cc0 + 1) ^ (row & 15)) * 4]; \
                bf16x8 bfr;                                                     \
                bfr[0] = (short)f2bf_rn(x0.x); bfr[1] = (short)f2bf_rn(x0.y);   \
                bfr[2] = (short)f2bf_rn(x0.z); bfr[3] = (short)f2bf_rn(x0.w);   \
                bfr[4] = (short)f2bf_rn(x1.x); bfr[5] = (short)f2bf_rn(x1.y);   \
                bfr[6] = (short)f2bf_rn(x1.z); bfr[7] = (short)f2bf_rn(x1.w);   \
                _Pragma("unroll")                                               \
                for (int ms = 0; ms < 4; ++ms)                                  \
                    acc[ms][nt] = __builtin_amdgcn_mfma_f32_16x16x32_bf16(      \
                        af[ms], bfr, acc[ms][nt], 0, 0, 0);                     \
            }                                                                   \
        }                                                                       \
    }

    STAGE(0, 0)
    STAGE(1, 64)
    for (int kt = 0; kt < 15; ++kt) {
        const int buf = kt & 1;
        wait_vm8();
        CONSUME(buf, kt * 64)
        if (kt + 2 < 16) { lds_war_guard(); STAGE(buf, (kt + 2) * 64) }
    }
    wait_vm0();
    CONSUME(1, 15 * 64)
#undef STAGE
#undef CONSUME

#pragma unroll
    for (int nt = 0; nt < 2; ++nt) {
        int v = v0 + w * 32 + nt * 16 + li;
        if (v < V) {
            float bov = bo[v];
#pragma unroll
            for (int ms = 0; ms < 4; ++ms)
#pragma unroll
                for (int j = 0; j < 4; ++j)
                    out[(size_t)(ms * 16 + qu * 4 + j) * V + v] = acc[ms][nt][j] + bov;
        }
    }
}

// ---------------------------------------------------------------------------
extern "C" void kernel_launch(void* const* d_in, const int* in_sizes, int n_in,
                              void* d_out, int out_size, void* d_ws, size_t ws_size,
                              hipStream_t stream) {
    (void)in_sizes; (void)n_in; (void)out_size; (void)ws_size;
    const int*   seq = (const int*)d_in[0];
    const float* h0  = (const float*)d_in[1];
    const float* enc = (const float*)d_in[2];
    const float* emb = (const float*)d_in[3];
    const float* Wih = (const float*)d_in[4];
    const float* Whh = (const float*)d_in[5];
    const float* bih = (const float*)d_in[6];
    const float* bhh = (const float*)d_in[7];
    const float* Wa  = (const float*)d_in[8];
    // d_in[9] = b_a: softmax over t is invariant to the per-b constant h·b_a -> unused
    const float* Wc  = (const float*)d_in[10];
    const float* bc  = (const float*)d_in[11];
    const float* Wo  = (const float*)d_in[12];
    const float* bo  = (const float*)d_in[13];

    float* out = (float*)d_out;
    float* hid = out + (size_t)B * V;

    float* ws   = (float*)d_ws;
    float* Pgi  = ws;                     // 786432
    float* Pgh  = Pgi + 786432;           // 786432
    float* Pu   = Pgh + 786432;           // 262144
    float* Pm   = Pu + 262144;            // 1024
    float* Pl   = Pm + 1024;              // 1024
    float* Pc   = Pl + 1024;              // 1048576 (4 MB)
    float* Pcg  = Pc + 1048576;           // 262144
    unsigned short* cat_bf = (unsigned short*)(Pcg + 262144);  // 131072 us
    unsigned short* co_bf  = cat_bf + 131072;                  // 65536 us

    k_gates<<<dim3(24, 4, 2), 256, 0, stream>>>(seq, emb, h0, Wih, Whh, Pgi, Pgh);
    k_gru<<<256, 256, 0, stream>>>(Pgi, Pgh, bih, bhh, h0, cat_bf, hid);
    k_mfma_wa<<<dim3(8, 4), 256, 0, stream>>>(cat_bf, Wa, Pu);
    k_flash<<<1024, 256, 0, stream>>>(Pu, enc, Pm, Pl, Pc);
    k_fcomb<<<64, 256, 0, stream>>>(Pm, Pl, Pc, cat_bf);
    k_mfma_bt<<<dim3(8, 4), 256, 0, stream>>>(cat_bf, 2 * H, Wc, 2 * H, Pcg, H, 512);
    k_co<<<256, 256, 0, stream>>>(Pcg, bc, co_bf);
    k_out_mfma<<<(V + 127) / 128, 256, 0, stream>>>(co_bf, Wo, bo, out);
}

// Round 9
// 135.163 us; speedup vs baseline: 1.7286x; 1.0538x over previous
//
#include <hip/hip_runtime.h>
#include <hip/hip_bf16.h>
#include <cstdint>
#include <cstddef>

#define H 1024
#define V 50257
#define B 64
#define T 512

typedef __attribute__((ext_vector_type(8))) short bf16x8;
typedef __attribute__((ext_vector_type(4))) float f32x4;

__device__ __forceinline__ float sigmoidf_(float x) { return 1.0f / (1.0f + expf(-x)); }

__device__ __forceinline__ unsigned short f2bf_rn(float x) {
    __hip_bfloat16 h = __float2bfloat16(x);
    return __builtin_bit_cast(unsigned short, h);
}

__device__ __forceinline__ void gl_lds16(const float* g, float* l) {
    __builtin_amdgcn_global_load_lds(
        (const __attribute__((address_space(1))) unsigned*)g,
        (__attribute__((address_space(3))) unsigned*)l, 16, 0, 0);
}

// Counted per-wave waits (barrier-free pipeline). sched_barrier pins motion.
__device__ __forceinline__ void wait_vm8() {
    asm volatile("s_waitcnt vmcnt(8)" ::: "memory");
    __builtin_amdgcn_sched_barrier(0);
}
__device__ __forceinline__ void wait_vm0() {
    asm volatile("s_waitcnt vmcnt(0)" ::: "memory");
    __builtin_amdgcn_sched_barrier(0);
}
// Guard before re-staging into the buffer consumed this iteration (WAR on LDS).
__device__ __forceinline__ void lds_war_guard() {
    asm volatile("s_waitcnt lgkmcnt(0)" ::: "memory");
    __builtin_amdgcn_sched_barrier(0);
}

// ---------------------------------------------------------------------------
// Gate GEMMs: z=0: Pgi = bf16(emb[seq]) @ Wih^T ; z=1: Pgh = bf16(h0) @ Whh^T.
// M=64, BN=128, split-K (KC=256, grid.y=4). Barrier-free + 2-ahead vmcnt.
__global__ __launch_bounds__(256) void k_gates(const int* __restrict__ seq,
                                               const float* __restrict__ emb,
                                               const float* __restrict__ h0,
                                               const float* __restrict__ Wih,
                                               const float* __restrict__ Whh,
                                               float* __restrict__ Pgi,
                                               float* __restrict__ Pgh) {
    __shared__ __align__(16) float Bs[2][128 * 64];   // 32 KB x2
    const int z = blockIdx.z;
    const float* Bm = z ? Whh : Wih;
    float* C = (z ? Pgh : Pgi) + (size_t)blockIdx.y * 64 * (3 * H);
    const int t = threadIdx.x;
    const int w = t >> 6, lane = t & 63;
    const int li = lane & 15, qu = lane >> 4;
    const int n0 = blockIdx.x * 128;
    const int k0 = blockIdx.y * 256;
    const int N = 3 * H;

    const float* Arow[4];
#pragma unroll
    for (int ms = 0; ms < 4; ++ms) {
        int m = ms * 16 + li;
        Arow[ms] = z ? (h0 + (size_t)m * H) : (emb + (size_t)seq[m] * H);
    }

    f32x4 acc[4][2];
#pragma unroll
    for (int ms = 0; ms < 4; ++ms)
#pragma unroll
        for (int nt = 0; nt < 2; ++nt) acc[ms][nt] = (f32x4){0.f, 0.f, 0.f, 0.f};

#define STG(BUF, KK)                                                            \
    {                                                                           \
        _Pragma("unroll")                                                       \
        for (int j = 0; j < 8; ++j) {                                           \
            int cidx = (w * 8 + j) * 64 + lane;                                 \
            int row = cidx >> 4, cs = cidx & 15;                                \
            int cg = cs ^ (row & 15);                                           \
            const float* gp = Bm + (size_t)(n0 + row) * H + (KK) + cg * 4;      \
            gl_lds16(gp, &Bs[BUF][(w * 8 + j) * 256]);                          \
        }                                                                       \
    }

#define CONSUME(BUF, KK)                                                        \
    {                                                                           \
        _Pragma("unroll")                                                       \
        for (int ks = 0; ks < 2; ++ks) {                                        \
            bf16x8 af[4];                                                       \
            _Pragma("unroll")                                                   \
            for (int ms = 0; ms < 4; ++ms) {                                    \
                float4 a0 = *(const float4*)&Arow[ms][(KK) + ks * 32 + qu * 8]; \
                float4 a1 = *(const float4*)&Arow[ms][(KK) + ks * 32 + qu * 8 + 4]; \
                af[ms][0] = (short)f2bf_rn(a0.x); af[ms][1] = (short)f2bf_rn(a0.y); \
                af[ms][2] = (short)f2bf_rn(a0.z); af[ms][3] = (short)f2bf_rn(a0.w); \
                af[ms][4] = (short)f2bf_rn(a1.x); af[ms][5] = (short)f2bf_rn(a1.y); \
                af[ms][6] = (short)f2bf_rn(a1.z); af[ms][7] = (short)f2bf_rn(a1.w); \
            }                                                                   \
            _Pragma("unroll")                                                   \
            for (int nt = 0; nt < 2; ++nt) {                                    \
                int row = w * 32 + nt * 16 + li;                                \
                int cc0 = ks * 8 + qu * 2;                                      \
                float4 x0 = *(const float4*)&Bs[BUF][row * 64 + ((cc0)     ^ (row & 15)) * 4]; \
                float4 x1 = *(const float4*)&Bs[BUF][row * 64 + ((cc0 + 1) ^ (row & 15)) * 4]; \
                bf16x8 bfr;                                                     \
                bfr[0] = (short)f2bf_rn(x0.x); bfr[1] = (short)f2bf_rn(x0.y);   \
                bfr[2] = (short)f2bf_rn(x0.z); bfr[3] = (short)f2bf_rn(x0.w);   \
                bfr[4] = (short)f2bf_rn(x1.x); bfr[5] = (short)f2bf_rn(x1.y);   \
                bfr[6] = (short)f2bf_rn(x1.z); bfr[7] = (short)f2bf_rn(x1.w);   \
                _Pragma("unroll")                                               \
                for (int ms = 0; ms < 4; ++ms)                                  \
                    acc[ms][nt] = __builtin_amdgcn_mfma_f32_16x16x32_bf16(      \
                        af[ms], bfr, acc[ms][nt], 0, 0, 0);                     \
            }                                                                   \
        }                                                                       \
    }

    STG(0, k0)
    STG(1, k0 + 64)
    for (int kt = 0; kt < 3; ++kt) {
        const int buf = kt & 1;
        wait_vm8();
        CONSUME(buf, k0 + kt * 64)
        if (kt + 2 < 4) { lds_war_guard(); STG(buf, k0 + (kt + 2) * 64) }
    }
    wait_vm0();
    CONSUME(1, k0 + 3 * 64)
#undef STG
#undef CONSUME

#pragma unroll
    for (int nt = 0; nt < 2; ++nt) {
        int col = n0 + w * 32 + nt * 16 + li;
#pragma unroll
        for (int ms = 0; ms < 4; ++ms)
#pragma unroll
            for (int j = 0; j < 4; ++j)
                C[(size_t)(ms * 16 + qu * 4 + j) * N + col] = acc[ms][nt][j];
    }
}

// ---------------------------------------------------------------------------
// Wc GEMM via bf16 MFMA, B row-major-in-K. C[m,n] = sum_k A[m,k]*Bm[n,k].
// Barrier-free + 2-ahead counted vmcnt.  nsteps = KC/64 (>=2).
__global__ __launch_bounds__(256) void k_mfma_bt(const unsigned short* __restrict__ A,
                                                 int lda,
                                                 const float* __restrict__ Bm, int ldb,
                                                 float* __restrict__ Cp, int N, int KC) {
    __shared__ __align__(16) float Bs[2][128 * 64];   // 32 KB x2
    float* C = Cp + (size_t)blockIdx.y * 64 * N;
    const int t = threadIdx.x;
    const int w = t >> 6, lane = t & 63;
    const int li = lane & 15, qu = lane >> 4;
    const int n0 = blockIdx.x * 128;
    const int k0 = blockIdx.y * KC;
    const int nsteps = KC >> 6;

    f32x4 acc[4][2];
#pragma unroll
    for (int ms = 0; ms < 4; ++ms)
#pragma unroll
        for (int nt = 0; nt < 2; ++nt) acc[ms][nt] = (f32x4){0.f, 0.f, 0.f, 0.f};

#define STG(BUF, KK)                                                            \
    {                                                                           \
        _Pragma("unroll")                                                       \
        for (int j = 0; j < 8; ++j) {                                           \
            int cidx = (w * 8 + j) * 64 + lane;                                 \
            int row = cidx >> 4, cs = cidx & 15;                                \
            int cg = cs ^ (row & 15);                                           \
            const float* gp = Bm + (size_t)(n0 + row) * ldb + (KK) + cg * 4;    \
            gl_lds16(gp, &Bs[BUF][(w * 8 + j) * 256]);                          \
        }                                                                       \
    }

#define CONSUME(BUF, KK)                                                        \
    {                                                                           \
        _Pragma("unroll")                                                       \
        for (int ks = 0; ks < 2; ++ks) {                                        \
            bf16x8 af[4];                                                       \
            _Pragma("unroll")                                                   \
            for (int ms = 0; ms < 4; ++ms)                                      \
                af[ms] = *(const bf16x8*)&A[(size_t)(ms * 16 + li) * lda + (KK) + ks * 32 + qu * 8]; \
            _Pragma("unroll")                                                   \
            for (int nt = 0; nt < 2; ++nt) {                                    \
                int row = w * 32 + nt * 16 + li;                                \
                int cc0 = ks * 8 + qu * 2;                                      \
                float4 x0 = *(const float4*)&Bs[BUF][row * 64 + ((cc0)     ^ (row & 15)) * 4]; \
                float4 x1 = *(const float4*)&Bs[BUF][row * 64 + ((cc0 + 1) ^ (row & 15)) * 4]; \
                bf16x8 bfr;                                                     \
                bfr[0] = (short)f2bf_rn(x0.x); bfr[1] = (short)f2bf_rn(x0.y);   \
                bfr[2] = (short)f2bf_rn(x0.z); bfr[3] = (short)f2bf_rn(x0.w);   \
                bfr[4] = (short)f2bf_rn(x1.x); bfr[5] = (short)f2bf_rn(x1.y);   \
                bfr[6] = (short)f2bf_rn(x1.z); bfr[7] = (short)f2bf_rn(x1.w);   \
                _Pragma("unroll")                                               \
                for (int ms = 0; ms < 4; ++ms)                                  \
                    acc[ms][nt] = __builtin_amdgcn_mfma_f32_16x16x32_bf16(      \
                        af[ms], bfr, acc[ms][nt], 0, 0, 0);                     \
            }                                                                   \
        }                                                                       \
    }

    STG(0, k0)
    STG(1, k0 + 64)
    for (int kt = 0; kt < nsteps - 1; ++kt) {
        const int buf = kt & 1;
        wait_vm8();
        CONSUME(buf, k0 + kt * 64)
        if (kt + 2 < nsteps) { lds_war_guard(); STG(buf, k0 + (kt + 2) * 64) }
    }
    wait_vm0();
    CONSUME((nsteps - 1) & 1, k0 + (nsteps - 1) * 64)
#undef STG
#undef CONSUME

#pragma unroll
    for (int nt = 0; nt < 2; ++nt) {
        int col = n0 + w * 32 + nt * 16 + li;
#pragma unroll
        for (int ms = 0; ms < 4; ++ms)
#pragma unroll
            for (int j = 0; j < 4; ++j)
                C[(size_t)(ms * 16 + qu * 4 + j) * N + col] = acc[ms][nt][j];
    }
}

// ---------------------------------------------------------------------------
// u-GEMM (B column-major-in-K): Pu[m,n] += sum_k h[m,k] * Wa[k,n].
// Re-gridded for machine fill: BN=64, KC=128 -> dim3(16,8) = 128 blocks.
__global__ __launch_bounds__(256) void k_mfma_wa(const unsigned short* __restrict__ cat_bf,
                                                 const float* __restrict__ Wa,
                                                 float* __restrict__ Pu) {
    const int t = threadIdx.x;
    const int w = t >> 6, lane = t & 63;
    const int li = lane & 15, qu = lane >> 4;
    const int n0 = blockIdx.x * 64;        // 16 n-blocks
    const int k0 = blockIdx.y * 128;       // 8 K-chunks

    f32x4 acc[4];
#pragma unroll
    for (int ms = 0; ms < 4; ++ms) acc[ms] = (f32x4){0.f, 0.f, 0.f, 0.f};

    const int col = n0 + w * 16 + li;

    for (int kt = 0; kt < 2; ++kt) {
        const int kk = k0 + kt * 64;
#pragma unroll
        for (int ks = 0; ks < 2; ++ks) {
            bf16x8 af[4];
#pragma unroll
            for (int ms = 0; ms < 4; ++ms)
                af[ms] = *(const bf16x8*)&cat_bf[(size_t)(ms * 16 + li) * 2048 + kk + ks * 32 + qu * 8];
            const int kb = kk + ks * 32 + qu * 8;
            bf16x8 bfr;
#pragma unroll
            for (int e = 0; e < 8; ++e)
                bfr[e] = (short)f2bf_rn(Wa[(size_t)(kb + e) * H + col]);
#pragma unroll
            for (int ms = 0; ms < 4; ++ms)
                acc[ms] = __builtin_amdgcn_mfma_f32_16x16x32_bf16(
                    af[ms], bfr, acc[ms], 0, 0, 0);
        }
    }
    float* C = Pu + (size_t)blockIdx.y * 64 * H;
#pragma unroll
    for (int ms = 0; ms < 4; ++ms)
#pragma unroll
        for (int j = 0; j < 4; ++j)
            C[(size_t)(ms * 16 + qu * 4 + j) * H + col] = acc[ms][j];
}

// ---------------------------------------------------------------------------
// GRU combine: fp32 partial sums -> h. Writes hid (fp32) and cat_bf[:, :H].
__global__ void k_gru(const float* __restrict__ Pgi, const float* __restrict__ Pgh,
                      const float* __restrict__ bih, const float* __restrict__ bhh,
                      const float* __restrict__ h0, unsigned short* __restrict__ cat_bf,
                      float* __restrict__ hid) {
    int i = blockIdx.x * 256 + threadIdx.x;   // 65536
    int b = i >> 10, h = i & 1023;
    float gr = bih[h], gz = bih[H + h], gn = bih[2 * H + h];
    float hr = bhh[h], hz = bhh[H + h], hn = bhh[2 * H + h];
#pragma unroll
    for (int kt = 0; kt < 4; ++kt) {
        const float* pi = Pgi + (size_t)kt * B * 3 * H + (size_t)b * 3 * H;
        const float* ph = Pgh + (size_t)kt * B * 3 * H + (size_t)b * 3 * H;
        gr += pi[h]; gz += pi[H + h]; gn += pi[2 * H + h];
        hr += ph[h]; hz += ph[H + h]; hn += ph[2 * H + h];
    }
    float r = sigmoidf_(gr + hr);
    float z = sigmoidf_(gz + hz);
    float n = tanhf(gn + r * hn);
    float hv = (1.0f - z) * n + z * h0[i];
    cat_bf[(size_t)b * 2048 + h] = f2bf_rn(hv);
    hid[i] = hv;
}

// ---------------------------------------------------------------------------
// Flash attention: block = (b, 32-row chunk), 4 waves x 8 rows. Online softmax
// per wave, 4-wave LDS combine -> 1024 partial records (4 MB).
__global__ __launch_bounds__(256) void k_flash(const float* __restrict__ Pu,
                                               const float* __restrict__ enc,
                                               float* __restrict__ Pm,
                                               float* __restrict__ Pl,
                                               float* __restrict__ Pc) {
    const int b = blockIdx.x >> 4, ch = blockIdx.x & 15;
    const int w = threadIdx.x >> 6, lane = threadIdx.x & 63;

    float4 uu[4];
#pragma unroll
    for (int it = 0; it < 4; ++it) {
        int col = (it * 64 + lane) * 4;
        float4 s = *(const float4*)&Pu[(size_t)b * H + col];
#pragma unroll
        for (int kt = 1; kt < 8; ++kt) {
            float4 p = *(const float4*)&Pu[(size_t)kt * B * H + (size_t)b * H + col];
            s.x += p.x; s.y += p.y; s.z += p.z; s.w += p.w;
        }
        uu[it] = s;
    }

    float m = -3.4e38f, l = 0.f;
    float4 c[4] = {{0,0,0,0},{0,0,0,0},{0,0,0,0},{0,0,0,0}};
    const float* ebase = enc + ((size_t)b * T + ch * 32 + w * 8) * H;

#pragma unroll 2
    for (int tt = 0; tt < 8; ++tt) {
        float4 e[4];
#pragma unroll
        for (int it = 0; it < 4; ++it)
            e[it] = *(const float4*)&ebase[(size_t)tt * H + (it * 64 + lane) * 4];
        float s = 0.f;
#pragma unroll
        for (int it = 0; it < 4; ++it)
            s += uu[it].x * e[it].x + uu[it].y * e[it].y +
                 uu[it].z * e[it].z + uu[it].w * e[it].w;
#pragma unroll
        for (int o = 32; o; o >>= 1) s += __shfl_xor(s, o, 64);
        float mn = fmaxf(m, s);
        float scale = __expf(m - mn);
        float p = __expf(s - mn);
        l = l * scale + p;
#pragma unroll
        for (int it = 0; it < 4; ++it) {
            c[it].x = fmaf(p, e[it].x, c[it].x * scale);
            c[it].y = fmaf(p, e[it].y, c[it].y * scale);
            c[it].z = fmaf(p, e[it].z, c[it].z * scale);
            c[it].w = fmaf(p, e[it].w, c[it].w * scale);
        }
        m = mn;
    }

    __shared__ float Lm[4], Ll[4];
    __shared__ __align__(16) float Lc[4][H];
#pragma unroll
    for (int it = 0; it < 4; ++it)
        *(float4*)&Lc[w][(it * 64 + lane) * 4] = c[it];
    if (lane == 0) { Lm[w] = m; Ll[w] = l; }
    __syncthreads();

    float M = fmaxf(fmaxf(Lm[0], Lm[1]), fmaxf(Lm[2], Lm[3]));
    float e0 = __expf(Lm[0] - M), e1 = __expf(Lm[1] - M),
          e2 = __expf(Lm[2] - M), e3 = __expf(Lm[3] - M);
    float L = Ll[0] * e0 + Ll[1] * e1 + Ll[2] * e2 + Ll[3] * e3;
    int col = threadIdx.x * 4;
    float4 c0 = *(const float4*)&Lc[0][col];
    float4 c1 = *(const float4*)&Lc[1][col];
    float4 c2 = *(const float4*)&Lc[2][col];
    float4 c3 = *(const float4*)&Lc[3][col];
    float4 cc;
    cc.x = c0.x * e0 + c1.x * e1 + c2.x * e2 + c3.x * e3;
    cc.y = c0.y * e0 + c1.y * e1 + c2.y * e2 + c3.y * e3;
    cc.z = c0.z * e0 + c1.z * e1 + c2.z * e2 + c3.z * e3;
    cc.w = c0.w * e0 + c1.w * e1 + c2.w * e2 + c3.w * e3;
    const int rec = blockIdx.x;   // b*16 + ch
    if (threadIdx.x == 0) { Pm[rec] = M; Pl[rec] = L; }
    *(float4*)&Pc[(size_t)rec * H + col] = cc;
}

// Combine 16 chunk-partials per b -> context -> cat_bf[:, H:2H]
__global__ void k_fcomb(const float* __restrict__ Pm, const float* __restrict__ Pl,
                        const float* __restrict__ Pc, unsigned short* __restrict__ cat_bf) {
    const int b = blockIdx.x;
    const int col = threadIdx.x * 4;
    float M = -3.4e38f;
#pragma unroll
    for (int i = 0; i < 16; ++i) M = fmaxf(M, Pm[b * 16 + i]);
    float L = 0.f;
    float4 cc = {0, 0, 0, 0};
#pragma unroll 4
    for (int i = 0; i < 16; ++i) {
        float wgt = __expf(Pm[b * 16 + i] - M);
        L += Pl[b * 16 + i] * wgt;
        float4 p = *(const float4*)&Pc[(size_t)(b * 16 + i) * H + col];
        cc.x += wgt * p.x; cc.y += wgt * p.y;
        cc.z += wgt * p.z; cc.w += wgt * p.w;
    }
    float inv = 1.0f / L;
    ushort4 o;
    o.x = f2bf_rn(cc.x * inv); o.y = f2bf_rn(cc.y * inv);
    o.z = f2bf_rn(cc.z * inv); o.w = f2bf_rn(cc.w * inv);
    *(ushort4*)&cat_bf[(size_t)b * 2048 + 1024 + col] = o;
}

// co = tanh(sum partials + b_c), written as bf16  (16 K-partials now)
__global__ void k_co(const float* __restrict__ Pc, const float* __restrict__ bc,
                     unsigned short* __restrict__ co_bf) {
    int i = blockIdx.x * 256 + threadIdx.x;
    int h = i & 1023;
    float s = bc[h];
#pragma unroll
    for (int kt = 0; kt < 16; ++kt) s += Pc[kt * (B * H) + i];
    co_bf[i] = f2bf_rn(tanhf(s));
}

// ---------------------------------------------------------------------------
// Output GEMM: out[b,v] = sum_h co[b,h]*Wo[v,h] + bo[v].  BN=128, BK=64.
// Barrier-free wave-private LDS rows + 2-ahead counted-vmcnt staging.
__global__ __launch_bounds__(256) void k_out_mfma(const unsigned short* __restrict__ co_bf,
                                                  const float* __restrict__ Wo,
                                                  const float* __restrict__ bo,
                                                  float* __restrict__ out) {
    __shared__ __align__(16) float Bs[2][128 * 64];   // 32 KB x2
    const int t = threadIdx.x;
    const int w = t >> 6, lane = t & 63;
    const int li = lane & 15, qu = lane >> 4;
    const int v0 = blockIdx.x * 128;

    f32x4 acc[4][2];
#pragma unroll
    for (int ms = 0; ms < 4; ++ms)
#pragma unroll
        for (int nt = 0; nt < 2; ++nt) acc[ms][nt] = (f32x4){0.f, 0.f, 0.f, 0.f};

#define STAGE(BUF, KK)                                                          \
    {                                                                           \
        _Pragma("unroll")                                                       \
        for (int j = 0; j < 8; ++j) {                                           \
            int cidx = (w * 8 + j) * 64 + lane;                                 \
            int row = cidx >> 4, cs = cidx & 15;                                \
            int cg = cs ^ (row & 15);                                           \
            int vr = v0 + row; if (vr >= V) vr = V - 1;                         \
            const float* gp = Wo + (size_t)vr * H + (KK) + cg * 4;              \
            gl_lds16(gp, &Bs[BUF][(w * 8 + j) * 256]);                          \
        }                                                                       \
    }

#define CONSUME(BUF, KK)                                                        \
    {                                                                           \
        _Pragma("unroll")                                                       \
        for (int ks = 0; ks < 2; ++ks) {                                        \
            bf16x8 af[4];                                                       \
            _Pragma("unroll")                                                   \
            for (int ms = 0; ms < 4; ++ms)                                      \
                af[ms] = *(const bf16x8*)&co_bf[(size_t)(ms * 16 + li) * H + (KK) + ks * 32 + qu * 8]; \
            _Pragma("unroll")                                                   \
            for (int nt = 0; nt < 2; ++nt) {                                    \
                int row = w * 32 + nt * 16 + li;                                \
                int cc0 = ks * 8 + qu * 2;                                      \
                float4 x0 = *(const float4*)&Bs[BUF][row * 64 + ((cc0)     ^ (row & 15)) * 4]; \
                float4 x1 = *(const float4*)&Bs[BUF][row * 64 + ((cc0 + 1) ^ (row & 15)) * 4]; \
                bf16x8 bfr;                                                     \
                bfr[0] = (short)f2bf_rn(x0.x); bfr[1] = (short)f2bf_rn(x0.y);   \
                bfr[2] = (short)f2bf_rn(x0.z); bfr[3] = (short)f2bf_rn(x0.w);   \
                bfr[4] = (short)f2bf_rn(x1.x); bfr[5] = (short)f2bf_rn(x1.y);   \
                bfr[6] = (short)f2bf_rn(x1.z); bfr[7] = (short)f2bf_rn(x1.w);   \
                _Pragma("unroll")                                               \
                for (int ms = 0; ms < 4; ++ms)                                  \
                    acc[ms][nt] = __builtin_amdgcn_mfma_f32_16x16x32_bf16(      \
                        af[ms], bfr, acc[ms][nt], 0, 0, 0);                     \
            }                                                                   \
        }                                                                       \
    }

    STAGE(0, 0)
    STAGE(1, 64)
    for (int kt = 0; kt < 15; ++kt) {
        const int buf = kt & 1;
        wait_vm8();
        CONSUME(buf, kt * 64)
        if (kt + 2 < 16) { lds_war_guard(); STAGE(buf, (kt + 2) * 64) }
    }
    wait_vm0();
    CONSUME(1, 15 * 64)
#undef STAGE
#undef CONSUME

#pragma unroll
    for (int nt = 0; nt < 2; ++nt) {
        int v = v0 + w * 32 + nt * 16 + li;
        if (v < V) {
            float bov = bo[v];
#pragma unroll
            for (int ms = 0; ms < 4; ++ms)
#pragma unroll
                for (int j = 0; j < 4; ++j)
                    out[(size_t)(ms * 16 + qu * 4 + j) * V + v] = acc[ms][nt][j] + bov;
        }
    }
}

// ---------------------------------------------------------------------------
extern "C" void kernel_launch(void* const* d_in, const int* in_sizes, int n_in,
                              void* d_out, int out_size, void* d_ws, size_t ws_size,
                              hipStream_t stream) {
    (void)in_sizes; (void)n_in; (void)out_size; (void)ws_size;
    const int*   seq = (const int*)d_in[0];
    const float* h0  = (const float*)d_in[1];
    const float* enc = (const float*)d_in[2];
    const float* emb = (const float*)d_in[3];
    const float* Wih = (const float*)d_in[4];
    const float* Whh = (const float*)d_in[5];
    const float* bih = (const float*)d_in[6];
    const float* bhh = (const float*)d_in[7];
    const float* Wa  = (const float*)d_in[8];
    // d_in[9] = b_a: softmax over t is invariant to the per-b constant h·b_a -> unused
    const float* Wc  = (const float*)d_in[10];
    const float* bc  = (const float*)d_in[11];
    const float* Wo  = (const float*)d_in[12];
    const float* bo  = (const float*)d_in[13];

    float* out = (float*)d_out;
    float* hid = out + (size_t)B * V;

    float* ws   = (float*)d_ws;
    float* Pgi  = ws;                     // 786432
    float* Pgh  = Pgi + 786432;           // 786432
    float* Pu   = Pgh + 786432;           // 524288 (8 partials)
    float* Pm   = Pu + 524288;            // 1024
    float* Pl   = Pm + 1024;              // 1024
    float* Pc   = Pl + 1024;              // 1048576 (4 MB)
    float* Pcg  = Pc + 1048576;           // 1048576 (16 partials)
    unsigned short* cat_bf = (unsigned short*)(Pcg + 1048576); // 131072 us
    unsigned short* co_bf  = cat_bf + 131072;                  // 65536 us

    k_gates<<<dim3(24, 4, 2), 256, 0, stream>>>(seq, emb, h0, Wih, Whh, Pgi, Pgh);
    k_gru<<<256, 256, 0, stream>>>(Pgi, Pgh, bih, bhh, h0, cat_bf, hid);
    k_mfma_wa<<<dim3(16, 8), 256, 0, stream>>>(cat_bf, Wa, Pu);
    k_flash<<<1024, 256, 0, stream>>>(Pu, enc, Pm, Pl, Pc);
    k_fcomb<<<64, 256, 0, stream>>>(Pm, Pl, Pc, cat_bf);
    k_mfma_bt<<<dim3(8, 16), 256, 0, stream>>>(cat_bf, 2 * H, Wc, 2 * H, Pcg, H, 128);
    k_co<<<256, 256, 0, stream>>>(Pcg, bc, co_bf);
    k_out_mfma<<<(V + 127) / 128, 256, 0, stream>>>(co_bf, Wo, bo, out);
}